// Round 11
// baseline (1266.474 us; speedup 1.0000x reference)
//
#include <hip/hip_runtime.h>

typedef __attribute__((ext_vector_type(8))) __bf16 bf16x8;
typedef __attribute__((ext_vector_type(4))) float f32x4;

// ---------------- workspace layout (byte offsets) ----------------
#define OFF_PATCH 0ull          // bf16 12544x1024
#define OFF_X     25690112ull   // f32  max(3200x1024, 12544x512)
#define OFF_LN    51380224ull   // bf16 max(3200x1024, 12544x512)
#define OFF_QKV   64225280ull   // bf16 qkv / f32 dec_tok / f32 pred
#define OFF_HID   103022592ull  // bf16 max(12544x2048)
#define OFF_WP    154402816ull  // bf16 packed transposed weights
#define OFF_ORD   214695936ull  // int 12544
#define OFF_PART  214746112ull  // f32 4096

// bf16-element offsets inside packed-weight region
#define WP_PATCH   0ull
#define WP_ENC_QKV 786432ull
#define WP_ENC_WO  7077888ull
#define WP_ENC_W1  9175040ull
#define WP_ENC_W2  17563648ull
#define WP_E2D     25952256ull
#define WP_DEC_QKV 26476544ull
#define WP_DEC_WO  27262976ull
#define WP_DEC_W1  27525120ull
#define WP_DEC_W2  28573696ull
#define WP_PIX     29622272ull

#define OM_BF16 0
#define OM_F32  1
#define OM_ACC  2
#define OM_GELU 3

__device__ __forceinline__ float b2f(unsigned short u) {
    return __uint_as_float(((unsigned int)u) << 16);
}
__device__ __forceinline__ unsigned short f2b(float f) {
    unsigned int x = __float_as_uint(f);
    x += 0x7fffu + ((x >> 16) & 1u);
    return (unsigned short)(x >> 16);
}
// gelu(x) = 0.5x(1+tanh(u)) = x * sigmoid(2u), u = 0.79788456(x + 0.044715 x^3)
__device__ __forceinline__ float gelu_f(float x) {
    float u2 = 1.5957691216057308f * x * (1.f + 0.044715f * x * x);
    return x / (1.f + __expf(-u2));
}
__device__ __forceinline__ void gload16(const void* g, void* l) {
    __builtin_amdgcn_global_load_lds((const __attribute__((address_space(1))) void*)g,
                                     (__attribute__((address_space(3))) void*)l, 16, 0, 0);
}
// raw s_barrier with compiler memory fences (no waitcnt drain)
__device__ __forceinline__ void fbar() {
    asm volatile("" ::: "memory");
    __builtin_amdgcn_s_barrier();
    asm volatile("" ::: "memory");
}

// ---------------- merged weight pack: 15 weights, one launch ----------------
struct PackArgs {
    const float* src[15];
    unsigned long long dstOff[15];  // bf16-element offset in wp
    int K[15], N[15];
    int tileStart[16];
};
__global__ __launch_bounds__(256) void pack_all(PackArgs pa, unsigned short* __restrict__ wp) {
    __shared__ float tile[32][33];
    int t = blockIdx.x;
    int d = 0;
    while (d < 14 && t >= pa.tileStart[d + 1]) ++d;
    int local = t - pa.tileStart[d];
    int K = pa.K[d], N = pa.N[d];
    int ntn = N >> 5;
    int kt = (local / ntn) << 5, nt = (local % ntn) << 5;
    const float* in = pa.src[d];
    unsigned short* out = wp + pa.dstOff[d];
    int tx = threadIdx.x & 31, ty = threadIdx.x >> 5;  // 32 x 8
#pragma unroll
    for (int i = 0; i < 32; i += 8) tile[ty + i][tx] = in[(size_t)(kt + ty + i) * N + nt + tx];
    __syncthreads();
#pragma unroll
    for (int i = 0; i < 32; i += 8)
        out[(size_t)(nt + ty + i) * K + kt + tx] = f2b(tile[tx][ty + i]);
}

// ---------------- patchify: images -> Xp bf16 [12544][768] ----------------
__global__ __launch_bounds__(256) void patchify_kernel(const float* __restrict__ img,
                                                       unsigned short* __restrict__ Xp) {
    const long long total = 12544ll * 768;
    for (long long e = (long long)blockIdx.x * 256 + threadIdx.x; e < total;
         e += (long long)gridDim.x * 256) {
        int row = (int)(e / 768), k = (int)(e % 768);
        int b = row / 196, pi = row % 196;
        int py = pi / 14, px = pi % 14;
        int r = k / 48, rem = k % 48;
        int c = rem / 3, ch = rem % 3;
        long long src = (((long long)(b * 224 + py * 16 + r)) * 224 + (px * 16 + c)) * 3 + ch;
        Xp[e] = f2b(img[src]);
    }
}

// ---------------- gemmA: 128x128, B staged in LDS, A streamed + reg-prefetch ----------------
// C[MxN] (+=) A[MxK](bf16) @ Bt[NxK](bf16)^T over K range [z*Kc, (z+1)*Kc).
// 4 waves (2m x 2n). Per K-step: stB(t) [4 gload_lds] -> loadA(next) [8 reg loads]
// -> vmcnt(8) [completes prev-A(8)+B(4), leaves new A(8) in flight] -> barrier -> MFMA.
// vmcnt(0) only at the final step (prefetch skipped there, count stays exact).
// Requires nt = Kc/64 even (all call sites satisfy).
template <int OM, bool ATOMIC, bool GATHER>
__global__ __launch_bounds__(256) void gemmA(const unsigned short* __restrict__ A,
                                             const unsigned short* __restrict__ Bt,
                                             void* __restrict__ Cv,
                                             const float* __restrict__ bias,
                                             const int* __restrict__ gord,
                                             int M, int N, int K, int Kc) {
    __shared__ __align__(16) unsigned short Bs[128 * 64];  // 16 KB
    const int tid = threadIdx.x, wave = tid >> 6, lane = tid & 63;
    // bijective XCD remap (m204)
    int nwg = gridDim.x * gridDim.y;
    int orig = blockIdx.y * gridDim.x + blockIdx.x;
    int q = nwg >> 3, r8 = nwg & 7, xcd = orig & 7, off = orig >> 3;
    int wg = (xcd < r8 ? xcd * (q + 1) : r8 * (q + 1) + (xcd - r8) * q) + off;
    const int brow = (wg / gridDim.x) * 128, bcol = (wg % gridDim.x) * 128;
    const int kBeg = blockIdx.z * Kc;
    const int fr = lane & 15, fq = lane >> 4;
    const int wr = (wave >> 1) * 64, wc = (wave & 1) * 64;
    const int lr = lane >> 3;
    const int sca = ((lane & 7) ^ lr) * 8;  // inverse-swizzled source col (elems)
    // B staging sources: rows bcol + wave*32 + i*8 + lr
    const unsigned short* Bgp[4];
#pragma unroll
    for (int i = 0; i < 4; ++i) {
        int r = bcol + wave * 32 + i * 8 + lr;
        Bgp[i] = Bt + (size_t)r * K + kBeg + sca;
    }
    // A direct per-fragment row pointers (clamped; dup rows masked in epilogue)
    const unsigned short* Ap[4];
#pragma unroll
    for (int m = 0; m < 4; ++m) {
        int r = brow + wr + m * 16 + fr;
        if (r > M - 1) r = M - 1;
        if constexpr (GATHER) {
            int bb = r / 147, jj = r - bb * 147;
            r = bb * 196 + gord[bb * 196 + jj];
        }
        Ap[m] = A + (size_t)r * K + kBeg + fq * 8;
    }

    f32x4 acc[4][4];
#pragma unroll
    for (int m = 0; m < 4; ++m)
#pragma unroll
        for (int n = 0; n < 4; ++n) acc[m][n] = (f32x4){0.f, 0.f, 0.f, 0.f};

    const char* lds = (const char*)Bs;
    const int sw = (fr & 7) << 4;
    const int b0 = (wc + fr) * 128 + ((fq * 16) ^ sw);  // +n*2048 imm, ^kk*64

    bf16x8 afA[4][2], afB[4][2];
    auto loadA = [&](bf16x8(&af)[4][2], int t) {
#pragma unroll
        for (int m = 0; m < 4; ++m) {
            const unsigned short* p = Ap[m] + (t << 6);
            af[m][0] = *(const bf16x8*)p;
            af[m][1] = *(const bf16x8*)(p + 32);
        }
    };
    auto stB = [&](int t) {
#pragma unroll
        for (int i = 0; i < 4; ++i)
            gload16(Bgp[i] + (t << 6), Bs + (wave * 32 + i * 8) * 64);
    };
    auto compute = [&](bf16x8(&af)[4][2]) {
        __builtin_amdgcn_s_setprio(1);
#pragma unroll
        for (int kk = 0; kk < 2; ++kk) {
            const int kx = kk * 64;
            bf16x8 bf[4];
#pragma unroll
            for (int n = 0; n < 4; ++n)
                bf[n] = *(const bf16x8*)(lds + ((b0 ^ kx) + n * 2048));
#pragma unroll
            for (int m = 0; m < 4; ++m)
#pragma unroll
                for (int n = 0; n < 4; ++n)
                    acc[m][n] = __builtin_amdgcn_mfma_f32_16x16x32_bf16(af[m][kk], bf[n],
                                                                       acc[m][n], 0, 0, 0);
        }
        __builtin_amdgcn_s_setprio(0);
    };

    const int nt = Kc >> 6;  // even by construction
    loadA(afA, 0);
    for (int t = 0; t < nt; t += 2) {
        // even step: compute afA
        fbar();                       // all waves done reading Bs(t-1)
        stB(t);
        loadA(afB, t + 1);
        asm volatile("s_waitcnt vmcnt(8)" ::: "memory");  // prev-A + B(t) landed
        fbar();
        compute(afA);
        // odd step: compute afB
        fbar();
        stB(t + 1);
        if (t + 2 < nt) {
            loadA(afA, t + 2);
            asm volatile("s_waitcnt vmcnt(8)" ::: "memory");
        } else {
            asm volatile("s_waitcnt vmcnt(0)" ::: "memory");  // final drain
        }
        fbar();
        compute(afB);
    }

    const bool addBias = (bias != nullptr) && (kBeg == 0);
#pragma unroll
    for (int m = 0; m < 4; ++m) {
        int rb = brow + wr + m * 16 + fq * 4;
#pragma unroll
        for (int r = 0; r < 4; ++r) {
            int row = rb + r;
            if (row < M) {
#pragma unroll
                for (int n = 0; n < 4; ++n) {
                    int col = bcol + wc + n * 16 + fr;
                    float v = acc[m][n][r];
                    if (addBias) v += bias[col];
                    size_t o = (size_t)row * N + col;
                    if constexpr (ATOMIC) atomicAdd((float*)Cv + o, v);
                    else if constexpr (OM == OM_BF16) ((unsigned short*)Cv)[o] = f2b(v);
                    else if constexpr (OM == OM_F32) ((float*)Cv)[o] = v;
                    else if constexpr (OM == OM_ACC) ((float*)Cv)[o] += v;
                    else ((unsigned short*)Cv)[o] = f2b(gelu_f(v));
                }
            }
        }
    }
}

// ---------------- gemm3<128>: single-buffer both-staged (small shapes: e2d) ----------------
template <int OM>
__global__ __launch_bounds__(256) void gemm3s(const unsigned short* __restrict__ A,
                                              const unsigned short* __restrict__ Bt,
                                              void* __restrict__ Cv,
                                              const float* __restrict__ bias,
                                              int M, int N, int K) {
    __shared__ __align__(16) unsigned short S[2 * 128 * 64];
    const int tid = threadIdx.x, wave = tid >> 6, lane = tid & 63;
    int nwg = gridDim.x * gridDim.y;
    int orig = blockIdx.y * gridDim.x + blockIdx.x;
    int q = nwg >> 3, r8 = nwg & 7, xcd = orig & 7, off = orig >> 3;
    int wg = (xcd < r8 ? xcd * (q + 1) : r8 * (q + 1) + (xcd - r8) * q) + off;
    const int brow = (wg / gridDim.x) * 128, bcol = (wg % gridDim.x) * 128;
    const int fr = lane & 15, fq = lane >> 4;
    const int wr = (wave >> 1) * 64, wc = (wave & 1) * 64;
    const int lr = lane >> 3;
    const int sca = ((lane & 7) ^ lr) * 8;
    const unsigned short* Agp[4];
#pragma unroll
    for (int i = 0; i < 4; ++i) {
        int r = brow + wave * 32 + i * 8 + lr;
        if (r > M - 1) r = M - 1;
        Agp[i] = A + (size_t)r * K + sca;
    }
    const unsigned short* Bgp[4];
#pragma unroll
    for (int i = 0; i < 4; ++i) {
        int r = bcol + wave * 32 + i * 8 + lr;
        Bgp[i] = Bt + (size_t)r * K + sca;
    }
    f32x4 acc[4][4];
#pragma unroll
    for (int m = 0; m < 4; ++m)
#pragma unroll
        for (int n = 0; n < 4; ++n) acc[m][n] = (f32x4){0.f, 0.f, 0.f, 0.f};
    const char* lds = (const char*)S;
    const int sw = (fr & 7) << 4;
    const int a0 = (wr + fr) * 128 + ((fq * 16) ^ sw);
    const int b0 = 16384 + (wc + fr) * 128 + ((fq * 16) ^ sw);
    const int nt = K >> 6;
    for (int t = 0; t < nt; ++t) {
        __syncthreads();
        const int k0 = t << 6;
#pragma unroll
        for (int i = 0; i < 4; ++i) {
            gload16(Agp[i] + k0, S + (wave * 32 + i * 8) * 64);
            gload16(Bgp[i] + k0, S + 128 * 64 + (wave * 32 + i * 8) * 64);
        }
        __syncthreads();
#pragma unroll
        for (int kk = 0; kk < 2; ++kk) {
            const int kx = kk * 64;
            bf16x8 af[4], bf[4];
#pragma unroll
            for (int m = 0; m < 4; ++m) af[m] = *(const bf16x8*)(lds + ((a0 ^ kx) + m * 2048));
#pragma unroll
            for (int n = 0; n < 4; ++n) bf[n] = *(const bf16x8*)(lds + ((b0 ^ kx) + n * 2048));
#pragma unroll
            for (int m = 0; m < 4; ++m)
#pragma unroll
                for (int n = 0; n < 4; ++n)
                    acc[m][n] = __builtin_amdgcn_mfma_f32_16x16x32_bf16(af[m], bf[n],
                                                                       acc[m][n], 0, 0, 0);
        }
    }
#pragma unroll
    for (int m = 0; m < 4; ++m) {
        int rb = brow + wr + m * 16 + fq * 4;
#pragma unroll
        for (int r = 0; r < 4; ++r) {
            int row = rb + r;
            if (row < M) {
#pragma unroll
                for (int n = 0; n < 4; ++n) {
                    int col = bcol + wc + n * 16 + fr;
                    float v = acc[m][n][r];
                    if (bias) v += bias[col];
                    size_t o = (size_t)row * N + col;
                    if constexpr (OM == OM_F32) ((float*)Cv)[o] = v;
                    else ((unsigned short*)Cv)[o] = f2b(v);
                }
            }
        }
    }
}

// ---------------- MFMA attention: one block per (b,h) ----------------
template <int N, int H, int NW>
__global__ __launch_bounds__(NW * 64) void attn_mfma(const unsigned short* __restrict__ qkv,
                                                     unsigned short* __restrict__ out) {
    constexpr int Npad = ((N + 31) / 32) * 32;
    constexpr int NT = Npad / 16;
    constexpr int KS = Npad / 32;
    constexpr int PS = Npad + 8;
    constexpr int SQ = 3 * H * 64, SO = H * 64;
    __shared__ __align__(16) unsigned short Kl[Npad * 64];
    __shared__ __align__(16) unsigned short Vt[64 * PS];
    __shared__ __align__(16) unsigned short Pl[NW * 16 * PS];
    const int b = blockIdx.x / H, h = blockIdx.x % H;
    const unsigned short* base = qkv + (size_t)b * N * SQ;
    const int qoff = h * 64, koff = (H + h) * 64, voff = (2 * H + h) * 64;
    const int tid = threadIdx.x, wave = tid >> 6, lane = tid & 63;
    const int fr = lane & 15, fq = lane >> 4;

    for (int idx = tid; idx < Npad * 8; idx += NW * 64) {
        int row = idx >> 3, ch = idx & 7;
        uint4 v = {0u, 0u, 0u, 0u};
        if (row < N) v = *(const uint4*)(base + (size_t)row * SQ + koff + ch * 8);
        *(uint4*)((char*)Kl + row * 128 + ((ch * 16) ^ ((row & 7) << 4))) = v;
    }
    for (int idx = tid; idx < Npad * 32; idx += NW * 64) {
        int key = idx >> 5, d2 = (idx & 31) * 2;
        unsigned int v = 0;
        if (key < N) v = *(const unsigned int*)(base + (size_t)key * SQ + voff + d2);
        Vt[d2 * PS + key] = (unsigned short)(v & 0xffffu);
        Vt[(d2 + 1) * PS + key] = (unsigned short)(v >> 16);
    }
    __syncthreads();

    unsigned short* pw = Pl + wave * 16 * PS;
    for (int qt = wave; qt < NT; qt += NW) {
        const int q0 = qt * 16;
        int qr = q0 + fr;
        if (qr > N - 1) qr = N - 1;
        const unsigned short* qp = base + (size_t)qr * SQ + qoff + fq * 8;
        bf16x8 aq0 = *(const bf16x8*)qp;
        bf16x8 aq1 = *(const bf16x8*)(qp + 32);
        f32x4 sa[NT];
#pragma unroll
        for (int ct = 0; ct < NT; ++ct) sa[ct] = (f32x4){0.f, 0.f, 0.f, 0.f};
#pragma unroll
        for (int ct = 0; ct < NT; ++ct) {
            const char* kb = (const char*)Kl + (ct * 16 + fr) * 128;
            bf16x8 kf0 = *(const bf16x8*)(kb + ((fq * 16) ^ ((fr & 7) << 4)));
            bf16x8 kf1 = *(const bf16x8*)(kb + ((64 + fq * 16) ^ ((fr & 7) << 4)));
            sa[ct] = __builtin_amdgcn_mfma_f32_16x16x32_bf16(aq0, kf0, sa[ct], 0, 0, 0);
            sa[ct] = __builtin_amdgcn_mfma_f32_16x16x32_bf16(aq1, kf1, sa[ct], 0, 0, 0);
        }
        float mrow[4] = {-3e38f, -3e38f, -3e38f, -3e38f};
#pragma unroll
        for (int ct = 0; ct < NT; ++ct) {
            bool ok = (ct * 16 + fr) < N;
#pragma unroll
            for (int r = 0; r < 4; ++r) {
                float s = ok ? sa[ct][r] * 0.125f : -3e38f;
                sa[ct][r] = s;
                mrow[r] = fmaxf(mrow[r], s);
            }
        }
#pragma unroll
        for (int off = 1; off <= 8; off <<= 1)
#pragma unroll
            for (int r = 0; r < 4; ++r) mrow[r] = fmaxf(mrow[r], __shfl_xor(mrow[r], off));
        float ssum[4] = {0.f, 0.f, 0.f, 0.f};
#pragma unroll
        for (int ct = 0; ct < NT; ++ct)
#pragma unroll
            for (int r = 0; r < 4; ++r) {
                float p = __expf(sa[ct][r] - mrow[r]);
                sa[ct][r] = p;
                ssum[r] += p;
            }
#pragma unroll
        for (int off = 1; off <= 8; off <<= 1)
#pragma unroll
            for (int r = 0; r < 4; ++r) ssum[r] += __shfl_xor(ssum[r], off);
#pragma unroll
        for (int ct = 0; ct < NT; ++ct)
#pragma unroll
            for (int r = 0; r < 4; ++r)
                pw[(fq * 4 + r) * PS + ct * 16 + fr] = f2b(sa[ct][r]);
        f32x4 oa[4];
#pragma unroll
        for (int vt = 0; vt < 4; ++vt) oa[vt] = (f32x4){0.f, 0.f, 0.f, 0.f};
#pragma unroll
        for (int ks = 0; ks < KS; ++ks) {
            bf16x8 pa = *(const bf16x8*)(pw + fr * PS + ks * 32 + fq * 8);
#pragma unroll
            for (int vt = 0; vt < 4; ++vt) {
                bf16x8 vf = *(const bf16x8*)(&Vt[(vt * 16 + fr) * PS + ks * 32 + fq * 8]);
                oa[vt] = __builtin_amdgcn_mfma_f32_16x16x32_bf16(pa, vf, oa[vt], 0, 0, 0);
            }
        }
        float inv[4];
#pragma unroll
        for (int r = 0; r < 4; ++r) inv[r] = 1.f / ssum[r];
#pragma unroll
        for (int vt = 0; vt < 4; ++vt)
#pragma unroll
            for (int r = 0; r < 4; ++r) {
                int q = q0 + fq * 4 + r;
                if (q < N)
                    out[((size_t)b * N + q) * SO + h * 64 + vt * 16 + fr] =
                        f2b(oa[vt][r] * inv[r]);
            }
    }
}

// ---------------- stable argsort of 196 per batch ----------------
__global__ __launch_bounds__(256) void argsort_kernel(const float* __restrict__ rnd,
                                                      int* __restrict__ ord) {
    __shared__ float vals[196];
    int b = blockIdx.x, t = threadIdx.x;
    if (t < 196) vals[t] = rnd[b * 196 + t];
    __syncthreads();
    if (t < 196) {
        float v = vals[t];
        int rank = 0;
        for (int j = 0; j < 196; ++j) {
            float vj = vals[j];
            rank += (vj < v) || (vj == v && j < t);
        }
        ord[b * 196 + rank] = t;
    }
}

__global__ __launch_bounds__(256) void gather_unmasked(const unsigned short* __restrict__ patches,
                                                       const float* __restrict__ pos,
                                                       const int* __restrict__ ord,
                                                       float* __restrict__ xe) {
    int row = blockIdx.x;  // 0..3135
    int b = row / 49, i = row % 49;
    int src = ord[b * 196 + 147 + i];
    const unsigned short* pr = patches + ((size_t)(b * 196 + src) << 10);
    const float* pe = pos + ((size_t)src << 10);
    float* o = xe + ((size_t)row << 10);
    int d = threadIdx.x * 4;
    ushort4 pv = *(const ushort4*)(pr + d);
    float4 p4 = *(const float4*)(pe + d);
    float4 r;
    r.x = b2f(pv.x) + p4.x; r.y = b2f(pv.y) + p4.y;
    r.z = b2f(pv.z) + p4.z; r.w = b2f(pv.w) + p4.w;
    *(float4*)(o + d) = r;
}

// ---------------- LayerNorm: f32 in -> bf16 out ----------------
template <int L>
__global__ __launch_bounds__(256) void ln_kernel(const float* __restrict__ x,
                                                 unsigned short* __restrict__ y,
                                                 const float* __restrict__ sw,
                                                 const float* __restrict__ bw) {
    __shared__ float red[8];
    const int tid = threadIdx.x;
    const float* xr = x + (size_t)blockIdx.x * L;
    float sum = 0.f, sq = 0.f;
    for (int i = tid * 4; i < L; i += 1024) {
        float4 v = *(const float4*)(xr + i);
        sum += v.x + v.y + v.z + v.w;
        sq += v.x * v.x + v.y * v.y + v.z * v.z + v.w * v.w;
    }
    for (int off = 32; off; off >>= 1) {
        sum += __shfl_xor(sum, off);
        sq += __shfl_xor(sq, off);
    }
    int wave = tid >> 6, lane = tid & 63;
    if (lane == 0) { red[wave] = sum; red[4 + wave] = sq; }
    __syncthreads();
    float ts = red[0] + red[1] + red[2] + red[3];
    float tq = red[4] + red[5] + red[6] + red[7];
    float mean = ts / L;
    float inv = rsqrtf(tq / L - mean * mean + 1e-5f);
    unsigned short* yr = y + (size_t)blockIdx.x * L;
    for (int i = tid * 4; i < L; i += 1024) {
        float4 v = *(const float4*)(xr + i);
        float4 s4 = *(const float4*)(sw + i);
        float4 b4 = *(const float4*)(bw + i);
        ushort4 o;
        o.x = f2b((v.x - mean) * inv * s4.x + b4.x);
        o.y = f2b((v.y - mean) * inv * s4.y + b4.y);
        o.z = f2b((v.z - mean) * inv * s4.z + b4.z);
        o.w = f2b((v.w - mean) * inv * s4.w + b4.w);
        *(ushort4*)(yr + i) = o;
    }
}

__global__ __launch_bounds__(256) void scatter_tokens(const float* __restrict__ dec_tok,
                                                      const float* __restrict__ dec_pos,
                                                      const float* __restrict__ mask_tok,
                                                      const int* __restrict__ ord,
                                                      float* __restrict__ all_tok) {
    int e = blockIdx.x;  // 0..12543
    int b = e / 196, i = e % 196;
    int idx = ord[e];
    float* o = all_tok + ((size_t)(b * 196 + idx)) * 512;
    const float* dp = dec_pos + (size_t)idx * 512;
    int d = threadIdx.x * 4;
    if (d < 512) {
        float4 dv = *(const float4*)(dp + d);
        float4 sv;
        if (i < 147) sv = *(const float4*)(mask_tok + d);
        else sv = *(const float4*)(dec_tok + ((size_t)(b * 49 + (i - 147))) * 512 + d);
        float4 r = {sv.x + dv.x, sv.y + dv.y, sv.z + dv.z, sv.w + dv.w};
        *(float4*)(o + d) = r;
    }
}

__global__ __launch_bounds__(256) void loss_partial(const float* __restrict__ pred,
                                                    const unsigned short* __restrict__ patches,
                                                    const int* __restrict__ ord,
                                                    float* __restrict__ part) {
    __shared__ float red[8];
    float local = 0.f;
    const long long total = 9633792ll;  // 9408*1024
    for (long long e = (long long)blockIdx.x * 256 + threadIdx.x; e < total; e += 4096ll * 256) {
        int r = (int)(e >> 10), d = (int)(e & 1023);
        int b = r / 147, j = r % 147;
        int idx = ord[b * 196 + j];
        float t = b2f(patches[(((size_t)(b * 196 + idx)) << 10) + d]);
        float df = pred[e] - t;
        local += df * df;
    }
    for (int off = 32; off; off >>= 1) local += __shfl_xor(local, off);
    int wave = threadIdx.x >> 6, lane = threadIdx.x & 63;
    if (lane == 0) red[wave] = local;
    __syncthreads();
    if (threadIdx.x == 0) part[blockIdx.x] = red[0] + red[1] + red[2] + red[3];
}

__global__ __launch_bounds__(256) void loss_final(const float* __restrict__ part,
                                                  float* __restrict__ out) {
    __shared__ float red[8];
    float local = 0.f;
    for (int i = threadIdx.x; i < 4096; i += 256) local += part[i];
    for (int off = 32; off; off >>= 1) local += __shfl_xor(local, off);
    int wave = threadIdx.x >> 6, lane = threadIdx.x & 63;
    if (lane == 0) red[wave] = local;
    __syncthreads();
    if (threadIdx.x == 0) out[0] = (red[0] + red[1] + red[2] + red[3]) / 9633792.0f;
}

extern "C" void kernel_launch(void* const* d_in, const int* in_sizes, int n_in, void* d_out,
                              int out_size, void* d_ws, size_t ws_size, hipStream_t stream) {
    const float* images = (const float*)d_in[0];
    const float* rnd = (const float*)d_in[1];
    const float* patch_W = (const float*)d_in[2];
    const float* patch_b = (const float*)d_in[3];
    const float* pos_emb = (const float*)d_in[4];
    const float* enc_ln1s = (const float*)d_in[5];
    const float* enc_ln1b = (const float*)d_in[6];
    const float* enc_Wqkv = (const float*)d_in[7];
    const float* enc_Wo = (const float*)d_in[8];
    const float* enc_ln2s = (const float*)d_in[9];
    const float* enc_ln2b = (const float*)d_in[10];
    const float* enc_W1 = (const float*)d_in[11];
    const float* enc_b1 = (const float*)d_in[12];
    const float* enc_W2 = (const float*)d_in[13];
    const float* enc_b2 = (const float*)d_in[14];
    const float* enc_lnfs = (const float*)d_in[15];
    const float* enc_lnfb = (const float*)d_in[16];
    const float* e2d_W = (const float*)d_in[17];
    const float* e2d_b = (const float*)d_in[18];
    const float* mask_tok = (const float*)d_in[19];
    const float* dec_pos = (const float*)d_in[20];
    const float* dec_ln1s = (const float*)d_in[21];
    const float* dec_ln1b = (const float*)d_in[22];
    const float* dec_Wqkv = (const float*)d_in[23];
    const float* dec_Wo = (const float*)d_in[24];
    const float* dec_ln2s = (const float*)d_in[25];
    const float* dec_ln2b = (const float*)d_in[26];
    const float* dec_W1 = (const float*)d_in[27];
    const float* dec_b1 = (const float*)d_in[28];
    const float* dec_W2 = (const float*)d_in[29];
    const float* dec_b2 = (const float*)d_in[30];
    const float* dec_lnfs = (const float*)d_in[31];
    const float* dec_lnfb = (const float*)d_in[32];
    const float* pix_W = (const float*)d_in[33];
    const float* pix_b = (const float*)d_in[34];

    char* ws = (char*)d_ws;
    unsigned short* patches = (unsigned short*)(ws + OFF_PATCH);
    float* Rx = (float*)(ws + OFF_X);
    unsigned short* Rln = (unsigned short*)(ws + OFF_LN);
    unsigned short* RqkvB = (unsigned short*)(ws + OFF_QKV);
    float* RqkvF = (float*)(ws + OFF_QKV);
    unsigned short* Rhid = (unsigned short*)(ws + OFF_HID);
    unsigned short* wp = (unsigned short*)(ws + OFF_WP);
    int* ord = (int*)(ws + OFF_ORD);
    float* part = (float*)(ws + OFF_PART);
    float* out = (float*)d_out;

    // ---- merged weight pack (15 weights, one launch) ----
    PackArgs pa;
    int nd = 0, tiles = 0;
    auto ADDP = [&](const float* src, unsigned long long wpo, int K, int N) {
        pa.src[nd] = src; pa.dstOff[nd] = wpo; pa.K[nd] = K; pa.N[nd] = N;
        pa.tileStart[nd] = tiles;
        tiles += (K >> 5) * (N >> 5);
        ++nd;
    };
    ADDP(patch_W, WP_PATCH, 768, 1024);
    for (int l = 0; l < 2; ++l) {
        ADDP(enc_Wqkv + (size_t)l * 1024 * 3072, WP_ENC_QKV + (size_t)l * 3145728, 1024, 3072);
        ADDP(enc_Wo + (size_t)l * 1024 * 1024, WP_ENC_WO + (size_t)l * 1048576, 1024, 1024);
        ADDP(enc_W1 + (size_t)l * 1024 * 4096, WP_ENC_W1 + (size_t)l * 4194304, 1024, 4096);
        ADDP(enc_W2 + (size_t)l * 4096 * 1024, WP_ENC_W2 + (size_t)l * 4194304, 4096, 1024);
    }
    ADDP(e2d_W, WP_E2D, 1024, 512);
    ADDP(dec_Wqkv, WP_DEC_QKV, 512, 1536);
    ADDP(dec_Wo, WP_DEC_WO, 512, 512);
    ADDP(dec_W1, WP_DEC_W1, 512, 2048);
    ADDP(dec_W2, WP_DEC_W2, 2048, 512);
    ADDP(pix_W, WP_PIX, 512, 1024);
    pa.tileStart[nd] = tiles;
    pack_all<<<tiles, 256, 0, stream>>>(pa, wp);

    // GEMM dispatch. S = split-K (atomic when >1). small -> gemm3s (both staged).
    auto GEMM = [&](int om, const unsigned short* A, size_t wpo, void* C, const float* bias,
                    int M, int N, int K, int S, bool small, const int* gord = nullptr) {
        const unsigned short* Bt = wp + wpo;
        int Kc = K / S;
        if (!small) {
            dim3 g(N / 128, (M + 127) / 128, S);
            if (gord) gemmA<OM_F32, false, true><<<g, 256, 0, stream>>>(A, Bt, C, bias, gord, M, N, K, Kc);
            else if (S > 1) gemmA<OM_ACC, true, false><<<g, 256, 0, stream>>>(A, Bt, C, bias, nullptr, M, N, K, Kc);
            else if (om == OM_BF16) gemmA<OM_BF16, false, false><<<g, 256, 0, stream>>>(A, Bt, C, bias, nullptr, M, N, K, Kc);
            else if (om == OM_F32) gemmA<OM_F32, false, false><<<g, 256, 0, stream>>>(A, Bt, C, bias, nullptr, M, N, K, Kc);
            else if (om == OM_ACC) gemmA<OM_ACC, false, false><<<g, 256, 0, stream>>>(A, Bt, C, bias, nullptr, M, N, K, Kc);
            else gemmA<OM_GELU, false, false><<<g, 256, 0, stream>>>(A, Bt, C, bias, nullptr, M, N, K, Kc);
        } else {
            dim3 g(N / 128, (M + 127) / 128, 1);
            if (om == OM_F32) gemm3s<OM_F32><<<g, 256, 0, stream>>>(A, Bt, C, bias, M, N, K);
            else gemm3s<OM_BF16><<<g, 256, 0, stream>>>(A, Bt, C, bias, M, N, K);
        }
    };

    // 1) patchify (Xp bf16 in Rhid), patches = Xp @ patch_W + b  (bf16)
    patchify_kernel<<<4096, 256, 0, stream>>>(images, Rhid);
    GEMM(OM_BF16, Rhid, WP_PATCH, patches, patch_b, 12544, 1024, 768, 1, false);
    // 2) argsort + gather unmasked (fp32 residual stream)
    argsort_kernel<<<64, 256, 0, stream>>>(rnd, ord);
    gather_unmasked<<<3136, 256, 0, stream>>>(patches, pos_emb, ord, Rx);

    // 3) encoder
    for (int l = 0; l < 2; ++l) {
        ln_kernel<1024><<<3136, 256, 0, stream>>>(Rx, Rln, enc_ln1s + l * 1024,
                                                  enc_ln1b + l * 1024);
        GEMM(OM_BF16, Rln, WP_ENC_QKV + (size_t)l * 3145728, RqkvB, nullptr, 3136, 3072, 1024,
             1, false);
        attn_mfma<49, 16, 4><<<64 * 16, 256, 0, stream>>>(RqkvB, Rhid);
        GEMM(OM_ACC, Rhid, WP_ENC_WO + (size_t)l * 1048576, Rx, nullptr, 3136, 1024, 1024, 4,
             false);
        ln_kernel<1024><<<3136, 256, 0, stream>>>(Rx, Rln, enc_ln2s + l * 1024,
                                                  enc_ln2b + l * 1024);
        GEMM(OM_GELU, Rln, WP_ENC_W1 + (size_t)l * 4194304, Rhid, enc_b1 + l * 4096, 3136,
             4096, 1024, 1, false);
        GEMM(OM_ACC, Rhid, WP_ENC_W2 + (size_t)l * 4194304, Rx, enc_b2 + l * 1024, 3136, 1024,
             4096, 4, false);
    }
    ln_kernel<1024><<<3136, 256, 0, stream>>>(Rx, Rln, enc_lnfs, enc_lnfb);

    // 4) e2d -> dec_tok (f32, in QKV region), scatter into decoder residual (f32)
    GEMM(OM_F32, Rln, WP_E2D, RqkvF, e2d_b, 3136, 512, 1024, 1, true);
    scatter_tokens<<<12544, 256, 0, stream>>>(RqkvF, dec_pos, mask_tok, ord, Rx);

    // 5) decoder
    ln_kernel<512><<<12544, 256, 0, stream>>>(Rx, Rln, dec_ln1s, dec_ln1b);
    GEMM(OM_BF16, Rln, WP_DEC_QKV, RqkvB, nullptr, 12544, 1536, 512, 1, false);
    attn_mfma<196, 8, 8><<<64 * 8, 512, 0, stream>>>(RqkvB, Rhid);
    GEMM(OM_ACC, Rhid, WP_DEC_WO, Rx, nullptr, 12544, 512, 512, 2, false);
    ln_kernel<512><<<12544, 256, 0, stream>>>(Rx, Rln, dec_ln2s, dec_ln2b);
    GEMM(OM_GELU, Rln, WP_DEC_W1, Rhid, dec_b1, 12544, 2048, 512, 1, false);
    GEMM(OM_ACC, Rhid, WP_DEC_W2, Rx, dec_b2, 12544, 512, 2048, 2, false);
    ln_kernel<512><<<12544, 256, 0, stream>>>(Rx, Rln, dec_lnfs, dec_lnfb);

    // 6) pix head with fused masked-gather (pred f32 in QKV region), MSE
    GEMM(OM_F32, Rln, WP_PIX, RqkvF, pix_b, 9408, 1024, 512, 1, false, ord);
    loss_partial<<<4096, 256, 0, stream>>>(RqkvF, patches, ord, part);
    loss_final<<<1, 256, 0, stream>>>(part, out);
}

// Round 12
// 958.871 us; speedup vs baseline: 1.3208x; 1.3208x over previous
//
#include <hip/hip_runtime.h>

typedef __attribute__((ext_vector_type(8))) __bf16 bf16x8;
typedef __attribute__((ext_vector_type(4))) float f32x4;

// ---------------- workspace layout (byte offsets) ----------------
#define OFF_PATCH 0ull          // bf16 12544x1024
#define OFF_X     25690112ull   // f32  max(3200x1024, 12544x512)
#define OFF_LN    51380224ull   // bf16 max(3200x1024, 12544x512)
#define OFF_QKV   64225280ull   // bf16 qkv / f32 dec_tok / f32 pred
#define OFF_HID   103022592ull  // bf16 max(12544x2048)
#define OFF_WP    154402816ull  // bf16 packed transposed weights
#define OFF_ORD   214695936ull  // int 12544
#define OFF_PART  214746112ull  // f32 4096

// bf16-element offsets inside packed-weight region
#define WP_PATCH   0ull
#define WP_ENC_QKV 786432ull
#define WP_ENC_WO  7077888ull
#define WP_ENC_W1  9175040ull
#define WP_ENC_W2  17563648ull
#define WP_E2D     25952256ull
#define WP_DEC_QKV 26476544ull
#define WP_DEC_WO  27262976ull
#define WP_DEC_W1  27525120ull
#define WP_DEC_W2  28573696ull
#define WP_PIX     29622272ull

#define OM_BF16 0
#define OM_F32  1
#define OM_ACC  2
#define OM_GELU 3

__device__ __forceinline__ float b2f(unsigned short u) {
    return __uint_as_float(((unsigned int)u) << 16);
}
__device__ __forceinline__ unsigned short f2b(float f) {
    unsigned int x = __float_as_uint(f);
    x += 0x7fffu + ((x >> 16) & 1u);
    return (unsigned short)(x >> 16);
}
// gelu(x) = 0.5x(1+tanh(u)) = x * sigmoid(2u), u = 0.79788456(x + 0.044715 x^3)
__device__ __forceinline__ float gelu_f(float x) {
    float u2 = 1.5957691216057308f * x * (1.f + 0.044715f * x * x);
    return x / (1.f + __expf(-u2));
}
__device__ __forceinline__ void gload16(const void* g, void* l) {
    __builtin_amdgcn_global_load_lds((const __attribute__((address_space(1))) void*)g,
                                     (__attribute__((address_space(3))) void*)l, 16, 0, 0);
}

// ---------------- merged weight pack: 15 weights, one launch ----------------
struct PackArgs {
    const float* src[15];
    unsigned long long dstOff[15];  // bf16-element offset in wp
    int K[15], N[15];
    int tileStart[16];
};
__global__ __launch_bounds__(256) void pack_all(PackArgs pa, unsigned short* __restrict__ wp) {
    __shared__ float tile[32][33];
    int t = blockIdx.x;
    int d = 0;
    while (d < 14 && t >= pa.tileStart[d + 1]) ++d;
    int local = t - pa.tileStart[d];
    int K = pa.K[d], N = pa.N[d];
    int ntn = N >> 5;
    int kt = (local / ntn) << 5, nt = (local % ntn) << 5;
    const float* in = pa.src[d];
    unsigned short* out = wp + pa.dstOff[d];
    int tx = threadIdx.x & 31, ty = threadIdx.x >> 5;  // 32 x 8
#pragma unroll
    for (int i = 0; i < 32; i += 8) tile[ty + i][tx] = in[(size_t)(kt + ty + i) * N + nt + tx];
    __syncthreads();
#pragma unroll
    for (int i = 0; i < 32; i += 8)
        out[(size_t)(nt + ty + i) * K + kt + tx] = f2b(tile[tx][ty + i]);
}

// ---------------- patchify: images -> Xp bf16 [12544][768] ----------------
__global__ __launch_bounds__(256) void patchify_kernel(const float* __restrict__ img,
                                                       unsigned short* __restrict__ Xp) {
    const long long total = 12544ll * 768;
    for (long long e = (long long)blockIdx.x * 256 + threadIdx.x; e < total;
         e += (long long)gridDim.x * 256) {
        int row = (int)(e / 768), k = (int)(e % 768);
        int b = row / 196, pi = row % 196;
        int py = pi / 14, px = pi % 14;
        int r = k / 48, rem = k % 48;
        int c = rem / 3, ch = rem % 3;
        long long src = (((long long)(b * 224 + py * 16 + r)) * 224 + (px * 16 + c)) * 3 + ch;
        Xp[e] = f2b(img[src]);
    }
}

// ---------------- gemmW: 256x256 tile, single-buffer 64KB LDS, split-K ----------------
// C[MxN] (+=) A[MxK](bf16) @ Bt[NxK](bf16)^T over K range [z*Kc, (z+1)*Kc).
// 8 waves (2m x 4n), per-wave 128x64 out (MR=8, NR=4). 2-barrier K-step.
template <int OM, bool ATOMIC>
__global__ __launch_bounds__(512) void gemmW(const unsigned short* __restrict__ A,
                                             const unsigned short* __restrict__ Bt,
                                             void* __restrict__ Cv,
                                             const float* __restrict__ bias,
                                             int M, int N, int K, int Kc) {
    __shared__ __align__(16) unsigned short S[2 * 256 * 64];  // A 32KB | B 32KB
    const int tid = threadIdx.x, w = tid >> 6, lane = tid & 63;
    const int wm = w >> 2, wn = w & 3;
    // bijective XCD remap (m204)
    int nwg = gridDim.x * gridDim.y;
    int orig = blockIdx.y * gridDim.x + blockIdx.x;
    int q = nwg >> 3, r8 = nwg & 7, xcd = orig & 7, off = orig >> 3;
    int wg = (xcd < r8 ? xcd * (q + 1) : r8 * (q + 1) + (xcd - r8) * q) + off;
    const int brow = (wg / gridDim.x) * 256, bcol = (wg % gridDim.x) * 256;
    const int kBeg = blockIdx.z * Kc;
    const int fr = lane & 15, fq = lane >> 4;
    const int lr = lane >> 3;
    const int sca = ((lane & 7) ^ lr) * 8;  // inverse-swizzled source col (elems)
    const unsigned short* Agp[4];
#pragma unroll
    for (int i = 0; i < 4; ++i) {
        int r = brow + w * 32 + i * 8 + lr;
        if (r > M - 1) r = M - 1;  // dup rows masked by epilogue guard
        Agp[i] = A + (size_t)r * K + kBeg + sca;
    }
    const unsigned short* Bgp[4];
#pragma unroll
    for (int i = 0; i < 4; ++i) {
        int r = bcol + w * 32 + i * 8 + lr;
        Bgp[i] = Bt + (size_t)r * K + kBeg + sca;
    }

    f32x4 acc[8][4];
#pragma unroll
    for (int m = 0; m < 8; ++m)
#pragma unroll
        for (int n = 0; n < 4; ++n) acc[m][n] = (f32x4){0.f, 0.f, 0.f, 0.f};

    const char* lds = (const char*)S;
    const int sw = (fr & 7) << 4;
    const int a0 = (wm * 128 + fr) * 128 + ((fq * 16) ^ sw);          // +m*2048, ^kk*64
    const int b0 = 32768 + (wn * 64 + fr) * 128 + ((fq * 16) ^ sw);   // +n*2048, ^kk*64

    const int nt = Kc >> 6;
    for (int t = 0; t < nt; ++t) {
        __syncthreads();
        const int k0 = t << 6;
#pragma unroll
        for (int i = 0; i < 4; ++i)
            gload16(Agp[i] + k0, S + (w * 32 + i * 8) * 64);
#pragma unroll
        for (int i = 0; i < 4; ++i)
            gload16(Bgp[i] + k0, S + 256 * 64 + (w * 32 + i * 8) * 64);
        __syncthreads();
        __builtin_amdgcn_s_setprio(1);
#pragma unroll
        for (int kk = 0; kk < 2; ++kk) {
            const int kx = kk * 64;
            bf16x8 af[8], bf[4];
#pragma unroll
            for (int m = 0; m < 8; ++m)
                af[m] = *(const bf16x8*)(lds + ((a0 ^ kx) + m * 2048));
#pragma unroll
            for (int n = 0; n < 4; ++n)
                bf[n] = *(const bf16x8*)(lds + ((b0 ^ kx) + n * 2048));
#pragma unroll
            for (int m = 0; m < 8; ++m)
#pragma unroll
                for (int n = 0; n < 4; ++n)
                    acc[m][n] = __builtin_amdgcn_mfma_f32_16x16x32_bf16(af[m], bf[n],
                                                                       acc[m][n], 0, 0, 0);
        }
        __builtin_amdgcn_s_setprio(0);
    }

    const bool addBias = (bias != nullptr) && (kBeg == 0);
#pragma unroll
    for (int m = 0; m < 8; ++m) {
        int rb = brow + wm * 128 + m * 16 + fq * 4;
#pragma unroll
        for (int r = 0; r < 4; ++r) {
            int row = rb + r;
            if (row < M) {
#pragma unroll
                for (int n = 0; n < 4; ++n) {
                    int col = bcol + wn * 64 + n * 16 + fr;
                    float v = acc[m][n][r];
                    if (addBias) v += bias[col];
                    size_t o = (size_t)row * N + col;
                    if constexpr (ATOMIC) atomicAdd((float*)Cv + o, v);
                    else if constexpr (OM == OM_BF16) ((unsigned short*)Cv)[o] = f2b(v);
                    else if constexpr (OM == OM_F32) ((float*)Cv)[o] = v;
                    else if constexpr (OM == OM_ACC) ((float*)Cv)[o] += v;
                    else ((unsigned short*)Cv)[o] = f2b(gelu_f(v));
                }
            }
        }
    }
}

// ---------------- gemm3: BMx128 tile, single-buffer LDS, split-K (R10 proven) ----------------
template <int BM, int OM, bool ATOMIC, bool GATHER>
__global__ __launch_bounds__((BM / 32) * 64) void gemm3(const unsigned short* __restrict__ A,
                                                        const unsigned short* __restrict__ Bt,
                                                        void* __restrict__ Cv,
                                                        const float* __restrict__ bias,
                                                        const int* __restrict__ gord,
                                                        int M, int N, int K, int Kc) {
    constexpr int WAVES = BM / 32;
    constexpr int BRW = 128 / WAVES;
    constexpr int NIB = BRW / 8;
    __shared__ __align__(16) unsigned short S[BM * 64 + 128 * 64];
    const int tid = threadIdx.x, wave = tid >> 6, lane = tid & 63;
    int nwg = gridDim.x * gridDim.y;
    int orig = blockIdx.y * gridDim.x + blockIdx.x;
    int q = nwg >> 3, r8 = nwg & 7, xcd = orig & 7, off = orig >> 3;
    int wg = (xcd < r8 ? xcd * (q + 1) : r8 * (q + 1) + (xcd - r8) * q) + off;
    const int brow = (wg / gridDim.x) * BM, bcol = (wg % gridDim.x) * 128;
    const int kBeg = blockIdx.z * Kc;
    const int fr = lane & 15, fq = lane >> 4;
    const int wr = (wave >> 1) * 64, wc = (wave & 1) * 64;
    const int lr = lane >> 3;
    const int sca = ((lane & 7) ^ lr) * 8;
    const unsigned short* Agp[4];
#pragma unroll
    for (int i = 0; i < 4; ++i) {
        int r = brow + wave * 32 + i * 8 + lr;
        if (r > M - 1) r = M - 1;
        if constexpr (GATHER) {
            int bb = r / 147, jj = r - bb * 147;
            r = bb * 196 + gord[bb * 196 + jj];
        }
        Agp[i] = A + (size_t)r * K + kBeg + sca;
    }
    const unsigned short* Bgp[NIB];
#pragma unroll
    for (int i = 0; i < NIB; ++i) {
        int r = bcol + wave * BRW + i * 8 + lr;
        Bgp[i] = Bt + (size_t)r * K + kBeg + sca;
    }

    f32x4 acc[4][4];
#pragma unroll
    for (int m = 0; m < 4; ++m)
#pragma unroll
        for (int n = 0; n < 4; ++n) acc[m][n] = (f32x4){0.f, 0.f, 0.f, 0.f};

    const char* lds = (const char*)S;
    const int sw = (fr & 7) << 4;
    const int a0 = (wr + fr) * 128 + ((fq * 16) ^ sw);
    const int b0 = BM * 128 + (wc + fr) * 128 + ((fq * 16) ^ sw);

    const int nt = Kc >> 6;
    for (int t = 0; t < nt; ++t) {
        __syncthreads();
        const int k0 = t << 6;
#pragma unroll
        for (int i = 0; i < 4; ++i)
            gload16(Agp[i] + k0, S + (wave * 32 + i * 8) * 64);
#pragma unroll
        for (int i = 0; i < NIB; ++i)
            gload16(Bgp[i] + k0, S + BM * 64 + (wave * BRW + i * 8) * 64);
        __syncthreads();
        __builtin_amdgcn_s_setprio(1);
#pragma unroll
        for (int kk = 0; kk < 2; ++kk) {
            const int kx = kk * 64;
            bf16x8 af[4], bf[4];
#pragma unroll
            for (int m = 0; m < 4; ++m)
                af[m] = *(const bf16x8*)(lds + ((a0 ^ kx) + m * 2048));
#pragma unroll
            for (int n = 0; n < 4; ++n)
                bf[n] = *(const bf16x8*)(lds + ((b0 ^ kx) + n * 2048));
#pragma unroll
            for (int m = 0; m < 4; ++m)
#pragma unroll
                for (int n = 0; n < 4; ++n)
                    acc[m][n] = __builtin_amdgcn_mfma_f32_16x16x32_bf16(af[m], bf[n],
                                                                       acc[m][n], 0, 0, 0);
        }
        __builtin_amdgcn_s_setprio(0);
    }

    const bool addBias = (bias != nullptr) && (kBeg == 0);
#pragma unroll
    for (int m = 0; m < 4; ++m) {
        int rb = brow + wr + m * 16 + fq * 4;
#pragma unroll
        for (int r = 0; r < 4; ++r) {
            int row = rb + r;
            if (row < M) {
#pragma unroll
                for (int n = 0; n < 4; ++n) {
                    int col = bcol + wc + n * 16 + fr;
                    float v = acc[m][n][r];
                    if (addBias) v += bias[col];
                    size_t o = (size_t)row * N + col;
                    if constexpr (ATOMIC) atomicAdd((float*)Cv + o, v);
                    else if constexpr (OM == OM_BF16) ((unsigned short*)Cv)[o] = f2b(v);
                    else if constexpr (OM == OM_F32) ((float*)Cv)[o] = v;
                    else if constexpr (OM == OM_ACC) ((float*)Cv)[o] += v;
                    else ((unsigned short*)Cv)[o] = f2b(gelu_f(v));
                }
            }
        }
    }
}

// ---------------- MFMA attention: one block per (b,h) ----------------
template <int N, int H, int NW>
__global__ __launch_bounds__(NW * 64) void attn_mfma(const unsigned short* __restrict__ qkv,
                                                     unsigned short* __restrict__ out) {
    constexpr int Npad = ((N + 31) / 32) * 32;
    constexpr int NT = Npad / 16;
    constexpr int KS = Npad / 32;
    constexpr int PS = Npad + 8;
    constexpr int SQ = 3 * H * 64, SO = H * 64;
    __shared__ __align__(16) unsigned short Kl[Npad * 64];
    __shared__ __align__(16) unsigned short Vt[64 * PS];
    __shared__ __align__(16) unsigned short Pl[NW * 16 * PS];
    const int b = blockIdx.x / H, h = blockIdx.x % H;
    const unsigned short* base = qkv + (size_t)b * N * SQ;
    const int qoff = h * 64, koff = (H + h) * 64, voff = (2 * H + h) * 64;
    const int tid = threadIdx.x, wave = tid >> 6, lane = tid & 63;
    const int fr = lane & 15, fq = lane >> 4;

    for (int idx = tid; idx < Npad * 8; idx += NW * 64) {
        int row = idx >> 3, ch = idx & 7;
        uint4 v = {0u, 0u, 0u, 0u};
        if (row < N) v = *(const uint4*)(base + (size_t)row * SQ + koff + ch * 8);
        *(uint4*)((char*)Kl + row * 128 + ((ch * 16) ^ ((row & 7) << 4))) = v;
    }
    for (int idx = tid; idx < Npad * 32; idx += NW * 64) {
        int key = idx >> 5, d2 = (idx & 31) * 2;
        unsigned int v = 0;
        if (key < N) v = *(const unsigned int*)(base + (size_t)key * SQ + voff + d2);
        Vt[d2 * PS + key] = (unsigned short)(v & 0xffffu);
        Vt[(d2 + 1) * PS + key] = (unsigned short)(v >> 16);
    }
    __syncthreads();

    unsigned short* pw = Pl + wave * 16 * PS;
    for (int qt = wave; qt < NT; qt += NW) {
        const int q0 = qt * 16;
        int qr = q0 + fr;
        if (qr > N - 1) qr = N - 1;
        const unsigned short* qp = base + (size_t)qr * SQ + qoff + fq * 8;
        bf16x8 aq0 = *(const bf16x8*)qp;
        bf16x8 aq1 = *(const bf16x8*)(qp + 32);
        f32x4 sa[NT];
#pragma unroll
        for (int ct = 0; ct < NT; ++ct) sa[ct] = (f32x4){0.f, 0.f, 0.f, 0.f};
#pragma unroll
        for (int ct = 0; ct < NT; ++ct) {
            const char* kb = (const char*)Kl + (ct * 16 + fr) * 128;
            bf16x8 kf0 = *(const bf16x8*)(kb + ((fq * 16) ^ ((fr & 7) << 4)));
            bf16x8 kf1 = *(const bf16x8*)(kb + ((64 + fq * 16) ^ ((fr & 7) << 4)));
            sa[ct] = __builtin_amdgcn_mfma_f32_16x16x32_bf16(aq0, kf0, sa[ct], 0, 0, 0);
            sa[ct] = __builtin_amdgcn_mfma_f32_16x16x32_bf16(aq1, kf1, sa[ct], 0, 0, 0);
        }
        float mrow[4] = {-3e38f, -3e38f, -3e38f, -3e38f};
#pragma unroll
        for (int ct = 0; ct < NT; ++ct) {
            bool ok = (ct * 16 + fr) < N;
#pragma unroll
            for (int r = 0; r < 4; ++r) {
                float s = ok ? sa[ct][r] * 0.125f : -3e38f;
                sa[ct][r] = s;
                mrow[r] = fmaxf(mrow[r], s);
            }
        }
#pragma unroll
        for (int off = 1; off <= 8; off <<= 1)
#pragma unroll
            for (int r = 0; r < 4; ++r) mrow[r] = fmaxf(mrow[r], __shfl_xor(mrow[r], off));
        float ssum[4] = {0.f, 0.f, 0.f, 0.f};
#pragma unroll
        for (int ct = 0; ct < NT; ++ct)
#pragma unroll
            for (int r = 0; r < 4; ++r) {
                float p = __expf(sa[ct][r] - mrow[r]);
                sa[ct][r] = p;
                ssum[r] += p;
            }
#pragma unroll
        for (int off = 1; off <= 8; off <<= 1)
#pragma unroll
            for (int r = 0; r < 4; ++r) ssum[r] += __shfl_xor(ssum[r], off);
#pragma unroll
        for (int ct = 0; ct < NT; ++ct)
#pragma unroll
            for (int r = 0; r < 4; ++r)
                pw[(fq * 4 + r) * PS + ct * 16 + fr] = f2b(sa[ct][r]);
        f32x4 oa[4];
#pragma unroll
        for (int vt = 0; vt < 4; ++vt) oa[vt] = (f32x4){0.f, 0.f, 0.f, 0.f};
#pragma unroll
        for (int ks = 0; ks < KS; ++ks) {
            bf16x8 pa = *(const bf16x8*)(pw + fr * PS + ks * 32 + fq * 8);
#pragma unroll
            for (int vt = 0; vt < 4; ++vt) {
                bf16x8 vf = *(const bf16x8*)(&Vt[(vt * 16 + fr) * PS + ks * 32 + fq * 8]);
                oa[vt] = __builtin_amdgcn_mfma_f32_16x16x32_bf16(pa, vf, oa[vt], 0, 0, 0);
            }
        }
        float inv[4];
#pragma unroll
        for (int r = 0; r < 4; ++r) inv[r] = 1.f / ssum[r];
#pragma unroll
        for (int vt = 0; vt < 4; ++vt)
#pragma unroll
            for (int r = 0; r < 4; ++r) {
                int q = q0 + fq * 4 + r;
                if (q < N)
                    out[((size_t)b * N + q) * SO + h * 64 + vt * 16 + fr] =
                        f2b(oa[vt][r] * inv[r]);
            }
    }
}

// ---------------- stable argsort of 196 per batch ----------------
__global__ __launch_bounds__(256) void argsort_kernel(const float* __restrict__ rnd,
                                                      int* __restrict__ ord) {
    __shared__ float vals[196];
    int b = blockIdx.x, t = threadIdx.x;
    if (t < 196) vals[t] = rnd[b * 196 + t];
    __syncthreads();
    if (t < 196) {
        float v = vals[t];
        int rank = 0;
        for (int j = 0; j < 196; ++j) {
            float vj = vals[j];
            rank += (vj < v) || (vj == v && j < t);
        }
        ord[b * 196 + rank] = t;
    }
}

__global__ __launch_bounds__(256) void gather_unmasked(const unsigned short* __restrict__ patches,
                                                       const float* __restrict__ pos,
                                                       const int* __restrict__ ord,
                                                       float* __restrict__ xe) {
    int row = blockIdx.x;  // 0..3135
    int b = row / 49, i = row % 49;
    int src = ord[b * 196 + 147 + i];
    const unsigned short* pr = patches + ((size_t)(b * 196 + src) << 10);
    const float* pe = pos + ((size_t)src << 10);
    float* o = xe + ((size_t)row << 10);
    int d = threadIdx.x * 4;
    ushort4 pv = *(const ushort4*)(pr + d);
    float4 p4 = *(const float4*)(pe + d);
    float4 r;
    r.x = b2f(pv.x) + p4.x; r.y = b2f(pv.y) + p4.y;
    r.z = b2f(pv.z) + p4.z; r.w = b2f(pv.w) + p4.w;
    *(float4*)(o + d) = r;
}

// ---------------- LayerNorm: f32 in -> bf16 out ----------------
template <int L>
__global__ __launch_bounds__(256) void ln_kernel(const float* __restrict__ x,
                                                 unsigned short* __restrict__ y,
                                                 const float* __restrict__ sw,
                                                 const float* __restrict__ bw) {
    __shared__ float red[8];
    const int tid = threadIdx.x;
    const float* xr = x + (size_t)blockIdx.x * L;
    float sum = 0.f, sq = 0.f;
    for (int i = tid * 4; i < L; i += 1024) {
        float4 v = *(const float4*)(xr + i);
        sum += v.x + v.y + v.z + v.w;
        sq += v.x * v.x + v.y * v.y + v.z * v.z + v.w * v.w;
    }
    for (int off = 32; off; off >>= 1) {
        sum += __shfl_xor(sum, off);
        sq += __shfl_xor(sq, off);
    }
    int wave = tid >> 6, lane = tid & 63;
    if (lane == 0) { red[wave] = sum; red[4 + wave] = sq; }
    __syncthreads();
    float ts = red[0] + red[1] + red[2] + red[3];
    float tq = red[4] + red[5] + red[6] + red[7];
    float mean = ts / L;
    float inv = rsqrtf(tq / L - mean * mean + 1e-5f);
    unsigned short* yr = y + (size_t)blockIdx.x * L;
    for (int i = tid * 4; i < L; i += 1024) {
        float4 v = *(const float4*)(xr + i);
        float4 s4 = *(const float4*)(sw + i);
        float4 b4 = *(const float4*)(bw + i);
        ushort4 o;
        o.x = f2b((v.x - mean) * inv * s4.x + b4.x);
        o.y = f2b((v.y - mean) * inv * s4.y + b4.y);
        o.z = f2b((v.z - mean) * inv * s4.z + b4.z);
        o.w = f2b((v.w - mean) * inv * s4.w + b4.w);
        *(ushort4*)(yr + i) = o;
    }
}

__global__ __launch_bounds__(256) void scatter_tokens(const float* __restrict__ dec_tok,
                                                      const float* __restrict__ dec_pos,
                                                      const float* __restrict__ mask_tok,
                                                      const int* __restrict__ ord,
                                                      float* __restrict__ all_tok) {
    int e = blockIdx.x;  // 0..12543
    int b = e / 196, i = e % 196;
    int idx = ord[e];
    float* o = all_tok + ((size_t)(b * 196 + idx)) * 512;
    const float* dp = dec_pos + (size_t)idx * 512;
    int d = threadIdx.x * 4;
    if (d < 512) {
        float4 dv = *(const float4*)(dp + d);
        float4 sv;
        if (i < 147) sv = *(const float4*)(mask_tok + d);
        else sv = *(const float4*)(dec_tok + ((size_t)(b * 49 + (i - 147))) * 512 + d);
        float4 r = {sv.x + dv.x, sv.y + dv.y, sv.z + dv.z, sv.w + dv.w};
        *(float4*)(o + d) = r;
    }
}

__global__ __launch_bounds__(256) void loss_partial(const float* __restrict__ pred,
                                                    const unsigned short* __restrict__ patches,
                                                    const int* __restrict__ ord,
                                                    float* __restrict__ part) {
    __shared__ float red[8];
    float local = 0.f;
    const long long total = 9633792ll;  // 9408*1024
    for (long long e = (long long)blockIdx.x * 256 + threadIdx.x; e < total; e += 4096ll * 256) {
        int r = (int)(e >> 10), d = (int)(e & 1023);
        int b = r / 147, j = r % 147;
        int idx = ord[b * 196 + j];
        float t = b2f(patches[(((size_t)(b * 196 + idx)) << 10) + d]);
        float df = pred[e] - t;
        local += df * df;
    }
    for (int off = 32; off; off >>= 1) local += __shfl_xor(local, off);
    int wave = threadIdx.x >> 6, lane = threadIdx.x & 63;
    if (lane == 0) red[wave] = local;
    __syncthreads();
    if (threadIdx.x == 0) part[blockIdx.x] = red[0] + red[1] + red[2] + red[3];
}

__global__ __launch_bounds__(256) void loss_final(const float* __restrict__ part,
                                                  float* __restrict__ out) {
    __shared__ float red[8];
    float local = 0.f;
    for (int i = threadIdx.x; i < 4096; i += 256) local += part[i];
    for (int off = 32; off; off >>= 1) local += __shfl_xor(local, off);
    int wave = threadIdx.x >> 6, lane = threadIdx.x & 63;
    if (lane == 0) red[wave] = local;
    __syncthreads();
    if (threadIdx.x == 0) out[0] = (red[0] + red[1] + red[2] + red[3]) / 9633792.0f;
}

extern "C" void kernel_launch(void* const* d_in, const int* in_sizes, int n_in, void* d_out,
                              int out_size, void* d_ws, size_t ws_size, hipStream_t stream) {
    const float* images = (const float*)d_in[0];
    const float* rnd = (const float*)d_in[1];
    const float* patch_W = (const float*)d_in[2];
    const float* patch_b = (const float*)d_in[3];
    const float* pos_emb = (const float*)d_in[4];
    const float* enc_ln1s = (const float*)d_in[5];
    const float* enc_ln1b = (const float*)d_in[6];
    const float* enc_Wqkv = (const float*)d_in[7];
    const float* enc_Wo = (const float*)d_in[8];
    const float* enc_ln2s = (const float*)d_in[9];
    const float* enc_ln2b = (const float*)d_in[10];
    const float* enc_W1 = (const float*)d_in[11];
    const float* enc_b1 = (const float*)d_in[12];
    const float* enc_W2 = (const float*)d_in[13];
    const float* enc_b2 = (const float*)d_in[14];
    const float* enc_lnfs = (const float*)d_in[15];
    const float* enc_lnfb = (const float*)d_in[16];
    const float* e2d_W = (const float*)d_in[17];
    const float* e2d_b = (const float*)d_in[18];
    const float* mask_tok = (const float*)d_in[19];
    const float* dec_pos = (const float*)d_in[20];
    const float* dec_ln1s = (const float*)d_in[21];
    const float* dec_ln1b = (const float*)d_in[22];
    const float* dec_Wqkv = (const float*)d_in[23];
    const float* dec_Wo = (const float*)d_in[24];
    const float* dec_ln2s = (const float*)d_in[25];
    const float* dec_ln2b = (const float*)d_in[26];
    const float* dec_W1 = (const float*)d_in[27];
    const float* dec_b1 = (const float*)d_in[28];
    const float* dec_W2 = (const float*)d_in[29];
    const float* dec_b2 = (const float*)d_in[30];
    const float* dec_lnfs = (const float*)d_in[31];
    const float* dec_lnfb = (const float*)d_in[32];
    const float* pix_W = (const float*)d_in[33];
    const float* pix_b = (const float*)d_in[34];

    char* ws = (char*)d_ws;
    unsigned short* patches = (unsigned short*)(ws + OFF_PATCH);
    float* Rx = (float*)(ws + OFF_X);
    unsigned short* Rln = (unsigned short*)(ws + OFF_LN);
    unsigned short* RqkvB = (unsigned short*)(ws + OFF_QKV);
    float* RqkvF = (float*)(ws + OFF_QKV);
    unsigned short* Rhid = (unsigned short*)(ws + OFF_HID);
    unsigned short* wp = (unsigned short*)(ws + OFF_WP);
    int* ord = (int*)(ws + OFF_ORD);
    float* part = (float*)(ws + OFF_PART);
    float* out = (float*)d_out;

    // ---- merged weight pack (15 weights, one launch) ----
    PackArgs pa;
    int nd = 0, tiles = 0;
    auto ADDP = [&](const float* src, unsigned long long wpo, int K, int N) {
        pa.src[nd] = src; pa.dstOff[nd] = wpo; pa.K[nd] = K; pa.N[nd] = N;
        pa.tileStart[nd] = tiles;
        tiles += (K >> 5) * (N >> 5);
        ++nd;
    };
    ADDP(patch_W, WP_PATCH, 768, 1024);
    for (int l = 0; l < 2; ++l) {
        ADDP(enc_Wqkv + (size_t)l * 1024 * 3072, WP_ENC_QKV + (size_t)l * 3145728, 1024, 3072);
        ADDP(enc_Wo + (size_t)l * 1024 * 1024, WP_ENC_WO + (size_t)l * 1048576, 1024, 1024);
        ADDP(enc_W1 + (size_t)l * 1024 * 4096, WP_ENC_W1 + (size_t)l * 4194304, 1024, 4096);
        ADDP(enc_W2 + (size_t)l * 4096 * 1024, WP_ENC_W2 + (size_t)l * 4194304, 4096, 1024);
    }
    ADDP(e2d_W, WP_E2D, 1024, 512);
    ADDP(dec_Wqkv, WP_DEC_QKV, 512, 1536);
    ADDP(dec_Wo, WP_DEC_WO, 512, 512);
    ADDP(dec_W1, WP_DEC_W1, 512, 2048);
    ADDP(dec_W2, WP_DEC_W2, 2048, 512);
    ADDP(pix_W, WP_PIX, 512, 1024);
    pa.tileStart[nd] = tiles;
    pack_all<<<tiles, 256, 0, stream>>>(pa, wp);

    // gemmW: 256x256 (large-M, N%256==0). gemm3: 256x128. S = split-K (atomic when >1).
    auto GEMMW = [&](int om, const unsigned short* A, size_t wpo, void* C, const float* bias,
                     int M, int N, int K, int S) {
        const unsigned short* Bt = wp + wpo;
        dim3 g(N / 256, (M + 255) / 256, S);
        int Kc = K / S;
        if (S > 1) gemmW<OM_ACC, true><<<g, 512, 0, stream>>>(A, Bt, C, bias, M, N, K, Kc);
        else if (om == OM_BF16) gemmW<OM_BF16, false><<<g, 512, 0, stream>>>(A, Bt, C, bias, M, N, K, Kc);
        else if (om == OM_F32) gemmW<OM_F32, false><<<g, 512, 0, stream>>>(A, Bt, C, bias, M, N, K, Kc);
        else if (om == OM_ACC) gemmW<OM_ACC, false><<<g, 512, 0, stream>>>(A, Bt, C, bias, M, N, K, Kc);
        else gemmW<OM_GELU, false><<<g, 512, 0, stream>>>(A, Bt, C, bias, M, N, K, Kc);
    };
    auto GEMM3 = [&](int om, const unsigned short* A, size_t wpo, void* C, const float* bias,
                     int M, int N, int K, int S, bool small, const int* gord = nullptr) {
        const unsigned short* Bt = wp + wpo;
        int Kc = K / S;
        if (!small) {
            dim3 g(N / 128, (M + 255) / 256, S);
            if (gord) gemm3<256, OM_F32, false, true><<<g, 512, 0, stream>>>(A, Bt, C, bias, gord, M, N, K, Kc);
            else if (S > 1) gemm3<256, OM_ACC, true, false><<<g, 512, 0, stream>>>(A, Bt, C, bias, nullptr, M, N, K, Kc);
            else if (om == OM_BF16) gemm3<256, OM_BF16, false, false><<<g, 512, 0, stream>>>(A, Bt, C, bias, nullptr, M, N, K, Kc);
            else if (om == OM_F32) gemm3<256, OM_F32, false, false><<<g, 512, 0, stream>>>(A, Bt, C, bias, nullptr, M, N, K, Kc);
            else if (om == OM_ACC) gemm3<256, OM_ACC, false, false><<<g, 512, 0, stream>>>(A, Bt, C, bias, nullptr, M, N, K, Kc);
            else gemm3<256, OM_GELU, false, false><<<g, 512, 0, stream>>>(A, Bt, C, bias, nullptr, M, N, K, Kc);
        } else {
            dim3 g(N / 128, (M + 127) / 128, S);
            if (om == OM_F32) gemm3<128, OM_F32, false, false><<<g, 256, 0, stream>>>(A, Bt, C, bias, nullptr, M, N, K, Kc);
            else gemm3<128, OM_BF16, false, false><<<g, 256, 0, stream>>>(A, Bt, C, bias, nullptr, M, N, K, Kc);
        }
    };

    // 1) patchify (Xp bf16 in Rhid), patches = Xp @ patch_W + b  (bf16)
    patchify_kernel<<<4096, 256, 0, stream>>>(images, Rhid);
    GEMMW(OM_BF16, Rhid, WP_PATCH, patches, patch_b, 12544, 1024, 768, 1);
    // 2) argsort + gather unmasked (fp32 residual stream)
    argsort_kernel<<<64, 256, 0, stream>>>(rnd, ord);
    gather_unmasked<<<3136, 256, 0, stream>>>(patches, pos_emb, ord, Rx);

    // 3) encoder (M=3136 -> 256x128 keeps the grid filled)
    for (int l = 0; l < 2; ++l) {
        ln_kernel<1024><<<3136, 256, 0, stream>>>(Rx, Rln, enc_ln1s + l * 1024,
                                                  enc_ln1b + l * 1024);
        GEMM3(OM_BF16, Rln, WP_ENC_QKV + (size_t)l * 3145728, RqkvB, nullptr, 3136, 3072, 1024,
              1, false);
        attn_mfma<49, 16, 4><<<64 * 16, 256, 0, stream>>>(RqkvB, Rhid);
        GEMM3(OM_ACC, Rhid, WP_ENC_WO + (size_t)l * 1048576, Rx, nullptr, 3136, 1024, 1024, 4,
              false);
        ln_kernel<1024><<<3136, 256, 0, stream>>>(Rx, Rln, enc_ln2s + l * 1024,
                                                  enc_ln2b + l * 1024);
        GEMM3(OM_GELU, Rln, WP_ENC_W1 + (size_t)l * 4194304, Rhid, enc_b1 + l * 4096, 3136,
              4096, 1024, 1, false);
        GEMM3(OM_ACC, Rhid, WP_ENC_W2 + (size_t)l * 4194304, Rx, enc_b2 + l * 1024, 3136, 1024,
              4096, 4, false);
    }
    ln_kernel<1024><<<3136, 256, 0, stream>>>(Rx, Rln, enc_lnfs, enc_lnfb);

    // 4) e2d -> dec_tok (f32, in QKV region), scatter into decoder residual (f32)
    GEMM3(OM_F32, Rln, WP_E2D, RqkvF, e2d_b, 3136, 512, 1024, 1, true);
    scatter_tokens<<<12544, 256, 0, stream>>>(RqkvF, dec_pos, mask_tok, ord, Rx);

    // 5) decoder (M=12544 -> 256x256 gemmW)
    ln_kernel<512><<<12544, 256, 0, stream>>>(Rx, Rln, dec_ln1s, dec_ln1b);
    GEMMW(OM_BF16, Rln, WP_DEC_QKV, RqkvB, nullptr, 12544, 1536, 512, 1);
    attn_mfma<196, 8, 8><<<64 * 8, 512, 0, stream>>>(RqkvB, Rhid);
    GEMMW(OM_ACC, Rhid, WP_DEC_WO, Rx, nullptr, 12544, 512, 512, 2);
    ln_kernel<512><<<12544, 256, 0, stream>>>(Rx, Rln, dec_ln2s, dec_ln2b);
    GEMMW(OM_GELU, Rln, WP_DEC_W1, Rhid, dec_b1, 12544, 2048, 512, 1);
    GEMMW(OM_ACC, Rhid, WP_DEC_W2, Rx, dec_b2, 12544, 512, 2048, 2);
    ln_kernel<512><<<12544, 256, 0, stream>>>(Rx, Rln, dec_lnfs, dec_lnfb);

    // 6) pix head with fused masked-gather (pred f32 in QKV region), MSE
    GEMM3(OM_F32, Rln, WP_PIX, RqkvF, pix_b, 9408, 1024, 512, 1, false, ord);
    loss_partial<<<4096, 256, 0, stream>>>(RqkvF, patches, ord, part);
    loss_final<<<1, 256, 0, stream>>>(part, out);
}

// Round 13
// 844.889 us; speedup vs baseline: 1.4990x; 1.1349x over previous
//
#include <hip/hip_runtime.h>

typedef __attribute__((ext_vector_type(8))) __bf16 bf16x8;
typedef __attribute__((ext_vector_type(4))) float f32x4;

// ---------------- workspace layout (byte offsets) ----------------
#define OFF_PATCH 0ull          // bf16 12544x1024
#define OFF_X     25690112ull   // f32  max(3200x1024, 12544x512)
#define OFF_LN    51380224ull   // bf16 max(3200x1024, 12544x512)
#define OFF_QKV   64225280ull   // bf16 qkv / f32 dec_tok / f32 pred
#define OFF_HID   103022592ull  // bf16 max(12544x2048)
#define OFF_WP    154402816ull  // bf16 packed transposed weights
#define OFF_ORD   214695936ull  // int 12544
#define OFF_PART  214746112ull  // f32 4096

// bf16-element offsets inside packed-weight region
#define WP_PATCH   0ull
#define WP_ENC_QKV 786432ull
#define WP_ENC_WO  7077888ull
#define WP_ENC_W1  9175040ull
#define WP_ENC_W2  17563648ull
#define WP_E2D     25952256ull
#define WP_DEC_QKV 26476544ull
#define WP_DEC_WO  27262976ull
#define WP_DEC_W1  27525120ull
#define WP_DEC_W2  28573696ull
#define WP_PIX     29622272ull

#define OM_BF16 0
#define OM_F32  1
#define OM_ACC  2
#define OM_GELU 3

__device__ __forceinline__ float b2f(unsigned short u) {
    return __uint_as_float(((unsigned int)u) << 16);
}
__device__ __forceinline__ unsigned short f2b(float f) {
    unsigned int x = __float_as_uint(f);
    x += 0x7fffu + ((x >> 16) & 1u);
    return (unsigned short)(x >> 16);
}
// gelu(x) = 0.5x(1+tanh(u)) = x * sigmoid(2u), u = 0.79788456(x + 0.044715 x^3)
__device__ __forceinline__ float gelu_f(float x) {
    float u2 = 1.5957691216057308f * x * (1.f + 0.044715f * x * x);
    return x / (1.f + __expf(-u2));
}
__device__ __forceinline__ void gload16(const void* g, void* l) {
    __builtin_amdgcn_global_load_lds((const __attribute__((address_space(1))) void*)g,
                                     (__attribute__((address_space(3))) void*)l, 16, 0, 0);
}

// ---------------- merged weight pack: 15 weights, one launch ----------------
struct PackArgs {
    const float* src[15];
    unsigned long long dstOff[15];  // bf16-element offset in wp
    int K[15], N[15];
    int tileStart[16];
};
__global__ __launch_bounds__(256) void pack_all(PackArgs pa, unsigned short* __restrict__ wp) {
    __shared__ float tile[32][33];
    int t = blockIdx.x;
    int d = 0;
    while (d < 14 && t >= pa.tileStart[d + 1]) ++d;
    int local = t - pa.tileStart[d];
    int K = pa.K[d], N = pa.N[d];
    int ntn = N >> 5;
    int kt = (local / ntn) << 5, nt = (local % ntn) << 5;
    const float* in = pa.src[d];
    unsigned short* out = wp + pa.dstOff[d];
    int tx = threadIdx.x & 31, ty = threadIdx.x >> 5;  // 32 x 8
#pragma unroll
    for (int i = 0; i < 32; i += 8) tile[ty + i][tx] = in[(size_t)(kt + ty + i) * N + nt + tx];
    __syncthreads();
#pragma unroll
    for (int i = 0; i < 32; i += 8)
        out[(size_t)(nt + ty + i) * K + kt + tx] = f2b(tile[tx][ty + i]);
}

// ---------------- patchify: images -> Xp bf16 [12544][768] ----------------
__global__ __launch_bounds__(256) void patchify_kernel(const float* __restrict__ img,
                                                       unsigned short* __restrict__ Xp) {
    const long long total = 12544ll * 768;
    for (long long e = (long long)blockIdx.x * 256 + threadIdx.x; e < total;
         e += (long long)gridDim.x * 256) {
        int row = (int)(e / 768), k = (int)(e % 768);
        int b = row / 196, pi = row % 196;
        int py = pi / 14, px = pi % 14;
        int r = k / 48, rem = k % 48;
        int c = rem / 3, ch = rem % 3;
        long long src = (((long long)(b * 224 + py * 16 + r)) * 224 + (px * 16 + c)) * 3 + ch;
        Xp[e] = f2b(img[src]);
    }
}

// ---------------- gemmV: 128x128 tile, 8 waves, 32KB single-buffer LDS ----------------
// C[MxN] (+=) A[MxK](bf16) @ Bt[NxK](bf16)^T over K range [z*Kc, (z+1)*Kc).
// 8 waves (4m x 2n), wave tile 32x64 (MR=2, NR=4) -> acc 32 VGPR -> up to
// 4 blocks/CU (LDS 32KB, wave cap 32/8) = 32 waves/CU for latency hiding.
template <int OM, bool ATOMIC, bool GATHER>
__global__ __launch_bounds__(512) void gemmV(const unsigned short* __restrict__ A,
                                             const unsigned short* __restrict__ Bt,
                                             void* __restrict__ Cv,
                                             const float* __restrict__ bias,
                                             const int* __restrict__ gord,
                                             int M, int N, int K, int Kc) {
    __shared__ __align__(16) unsigned short S[2 * 128 * 64];  // A 16KB | B 16KB
    const int tid = threadIdx.x, w = tid >> 6, lane = tid & 63;
    const int wm = w >> 1, wn = w & 1;
    // bijective XCD remap (m204)
    int nwg = gridDim.x * gridDim.y;
    int orig = blockIdx.y * gridDim.x + blockIdx.x;
    int q = nwg >> 3, r8 = nwg & 7, xcd = orig & 7, off = orig >> 3;
    int wg = (xcd < r8 ? xcd * (q + 1) : r8 * (q + 1) + (xcd - r8) * q) + off;
    const int brow = (wg / gridDim.x) * 128, bcol = (wg % gridDim.x) * 128;
    const int kBeg = blockIdx.z * Kc;
    const int fr = lane & 15, fq = lane >> 4;
    const int lr = lane >> 3;
    const int sca = ((lane & 7) ^ lr) * 8;  // inverse-swizzled source col (elems)
    // staging: A rows w*16 + i*8 + lr, B rows likewise (each wave 16 rows of each)
    const unsigned short* Agp[2];
#pragma unroll
    for (int i = 0; i < 2; ++i) {
        int r = brow + w * 16 + i * 8 + lr;
        if (r > M - 1) r = M - 1;  // dup rows masked by epilogue guard
        if constexpr (GATHER) {
            int bb = r / 147, jj = r - bb * 147;
            r = bb * 196 + gord[bb * 196 + jj];
        }
        Agp[i] = A + (size_t)r * K + kBeg + sca;
    }
    const unsigned short* Bgp[2];
#pragma unroll
    for (int i = 0; i < 2; ++i) {
        int r = bcol + w * 16 + i * 8 + lr;
        Bgp[i] = Bt + (size_t)r * K + kBeg + sca;
    }

    f32x4 acc[2][4];
#pragma unroll
    for (int m = 0; m < 2; ++m)
#pragma unroll
        for (int n = 0; n < 4; ++n) acc[m][n] = (f32x4){0.f, 0.f, 0.f, 0.f};

    const char* lds = (const char*)S;
    const int sw = (fr & 7) << 4;
    const int a0 = (wm * 32 + fr) * 128 + ((fq * 16) ^ sw);          // +m*2048, ^kk*64
    const int b0 = 16384 + (wn * 64 + fr) * 128 + ((fq * 16) ^ sw);  // +n*2048, ^kk*64

    const int nt = Kc >> 6;
    for (int t = 0; t < nt; ++t) {
        __syncthreads();  // prior compute's ds_reads done before overwrite
        const int k0 = t << 6;
#pragma unroll
        for (int i = 0; i < 2; ++i)
            gload16(Agp[i] + k0, S + (w * 16 + i * 8) * 64);
#pragma unroll
        for (int i = 0; i < 2; ++i)
            gload16(Bgp[i] + k0, S + 128 * 64 + (w * 16 + i * 8) * 64);
        __syncthreads();  // implicit vmcnt(0) drain: staged data visible
#pragma unroll
        for (int kk = 0; kk < 2; ++kk) {
            const int kx = kk * 64;
            bf16x8 af[2], bf[4];
#pragma unroll
            for (int m = 0; m < 2; ++m)
                af[m] = *(const bf16x8*)(lds + ((a0 ^ kx) + m * 2048));
#pragma unroll
            for (int n = 0; n < 4; ++n)
                bf[n] = *(const bf16x8*)(lds + ((b0 ^ kx) + n * 2048));
#pragma unroll
            for (int m = 0; m < 2; ++m)
#pragma unroll
                for (int n = 0; n < 4; ++n)
                    acc[m][n] = __builtin_amdgcn_mfma_f32_16x16x32_bf16(af[m], bf[n],
                                                                       acc[m][n], 0, 0, 0);
        }
    }

    const bool addBias = (bias != nullptr) && (kBeg == 0);
#pragma unroll
    for (int m = 0; m < 2; ++m) {
        int rb = brow + wm * 32 + m * 16 + fq * 4;
#pragma unroll
        for (int r = 0; r < 4; ++r) {
            int row = rb + r;
            if (row < M) {
#pragma unroll
                for (int n = 0; n < 4; ++n) {
                    int col = bcol + wn * 64 + n * 16 + fr;
                    float v = acc[m][n][r];
                    if (addBias) v += bias[col];
                    size_t o = (size_t)row * N + col;
                    if constexpr (ATOMIC) atomicAdd((float*)Cv + o, v);
                    else if constexpr (OM == OM_BF16) ((unsigned short*)Cv)[o] = f2b(v);
                    else if constexpr (OM == OM_F32) ((float*)Cv)[o] = v;
                    else if constexpr (OM == OM_ACC) ((float*)Cv)[o] += v;
                    else ((unsigned short*)Cv)[o] = f2b(gelu_f(v));
                }
            }
        }
    }
}

// ---------------- gemm3s: 128x128, 4 waves, both-staged (small shapes: e2d) ----------------
template <int OM>
__global__ __launch_bounds__(256) void gemm3s(const unsigned short* __restrict__ A,
                                              const unsigned short* __restrict__ Bt,
                                              void* __restrict__ Cv,
                                              const float* __restrict__ bias,
                                              int M, int N, int K) {
    __shared__ __align__(16) unsigned short S[2 * 128 * 64];
    const int tid = threadIdx.x, wave = tid >> 6, lane = tid & 63;
    int nwg = gridDim.x * gridDim.y;
    int orig = blockIdx.y * gridDim.x + blockIdx.x;
    int q = nwg >> 3, r8 = nwg & 7, xcd = orig & 7, off = orig >> 3;
    int wg = (xcd < r8 ? xcd * (q + 1) : r8 * (q + 1) + (xcd - r8) * q) + off;
    const int brow = (wg / gridDim.x) * 128, bcol = (wg % gridDim.x) * 128;
    const int fr = lane & 15, fq = lane >> 4;
    const int wr = (wave >> 1) * 64, wc = (wave & 1) * 64;
    const int lr = lane >> 3;
    const int sca = ((lane & 7) ^ lr) * 8;
    const unsigned short* Agp[4];
#pragma unroll
    for (int i = 0; i < 4; ++i) {
        int r = brow + wave * 32 + i * 8 + lr;
        if (r > M - 1) r = M - 1;
        Agp[i] = A + (size_t)r * K + sca;
    }
    const unsigned short* Bgp[4];
#pragma unroll
    for (int i = 0; i < 4; ++i) {
        int r = bcol + wave * 32 + i * 8 + lr;
        Bgp[i] = Bt + (size_t)r * K + sca;
    }
    f32x4 acc[4][4];
#pragma unroll
    for (int m = 0; m < 4; ++m)
#pragma unroll
        for (int n = 0; n < 4; ++n) acc[m][n] = (f32x4){0.f, 0.f, 0.f, 0.f};
    const char* lds = (const char*)S;
    const int sw = (fr & 7) << 4;
    const int a0 = (wr + fr) * 128 + ((fq * 16) ^ sw);
    const int b0 = 16384 + (wc + fr) * 128 + ((fq * 16) ^ sw);
    const int nt = K >> 6;
    for (int t = 0; t < nt; ++t) {
        __syncthreads();
        const int k0 = t << 6;
#pragma unroll
        for (int i = 0; i < 4; ++i) {
            gload16(Agp[i] + k0, S + (wave * 32 + i * 8) * 64);
            gload16(Bgp[i] + k0, S + 128 * 64 + (wave * 32 + i * 8) * 64);
        }
        __syncthreads();
#pragma unroll
        for (int kk = 0; kk < 2; ++kk) {
            const int kx = kk * 64;
            bf16x8 af[4], bf[4];
#pragma unroll
            for (int m = 0; m < 4; ++m) af[m] = *(const bf16x8*)(lds + ((a0 ^ kx) + m * 2048));
#pragma unroll
            for (int n = 0; n < 4; ++n) bf[n] = *(const bf16x8*)(lds + ((b0 ^ kx) + n * 2048));
#pragma unroll
            for (int m = 0; m < 4; ++m)
#pragma unroll
                for (int n = 0; n < 4; ++n)
                    acc[m][n] = __builtin_amdgcn_mfma_f32_16x16x32_bf16(af[m], bf[n],
                                                                       acc[m][n], 0, 0, 0);
        }
    }
#pragma unroll
    for (int m = 0; m < 4; ++m) {
        int rb = brow + wr + m * 16 + fq * 4;
#pragma unroll
        for (int r = 0; r < 4; ++r) {
            int row = rb + r;
            if (row < M) {
#pragma unroll
                for (int n = 0; n < 4; ++n) {
                    int col = bcol + wc + n * 16 + fr;
                    float v = acc[m][n][r];
                    if (bias) v += bias[col];
                    size_t o = (size_t)row * N + col;
                    if constexpr (OM == OM_F32) ((float*)Cv)[o] = v;
                    else ((unsigned short*)Cv)[o] = f2b(v);
                }
            }
        }
    }
}

// ---------------- MFMA attention: one block per (b,h) ----------------
template <int N, int H, int NW>
__global__ __launch_bounds__(NW * 64) void attn_mfma(const unsigned short* __restrict__ qkv,
                                                     unsigned short* __restrict__ out) {
    constexpr int Npad = ((N + 31) / 32) * 32;
    constexpr int NT = Npad / 16;
    constexpr int KS = Npad / 32;
    constexpr int PS = Npad + 8;
    constexpr int SQ = 3 * H * 64, SO = H * 64;
    __shared__ __align__(16) unsigned short Kl[Npad * 64];
    __shared__ __align__(16) unsigned short Vt[64 * PS];
    __shared__ __align__(16) unsigned short Pl[NW * 16 * PS];
    const int b = blockIdx.x / H, h = blockIdx.x % H;
    const unsigned short* base = qkv + (size_t)b * N * SQ;
    const int qoff = h * 64, koff = (H + h) * 64, voff = (2 * H + h) * 64;
    const int tid = threadIdx.x, wave = tid >> 6, lane = tid & 63;
    const int fr = lane & 15, fq = lane >> 4;

    for (int idx = tid; idx < Npad * 8; idx += NW * 64) {
        int row = idx >> 3, ch = idx & 7;
        uint4 v = {0u, 0u, 0u, 0u};
        if (row < N) v = *(const uint4*)(base + (size_t)row * SQ + koff + ch * 8);
        *(uint4*)((char*)Kl + row * 128 + ((ch * 16) ^ ((row & 7) << 4))) = v;
    }
    for (int idx = tid; idx < Npad * 32; idx += NW * 64) {
        int key = idx >> 5, d2 = (idx & 31) * 2;
        unsigned int v = 0;
        if (key < N) v = *(const unsigned int*)(base + (size_t)key * SQ + voff + d2);
        Vt[d2 * PS + key] = (unsigned short)(v & 0xffffu);
        Vt[(d2 + 1) * PS + key] = (unsigned short)(v >> 16);
    }
    __syncthreads();

    unsigned short* pw = Pl + wave * 16 * PS;
    for (int qt = wave; qt < NT; qt += NW) {
        const int q0 = qt * 16;
        int qr = q0 + fr;
        if (qr > N - 1) qr = N - 1;
        const unsigned short* qp = base + (size_t)qr * SQ + qoff + fq * 8;
        bf16x8 aq0 = *(const bf16x8*)qp;
        bf16x8 aq1 = *(const bf16x8*)(qp + 32);
        f32x4 sa[NT];
#pragma unroll
        for (int ct = 0; ct < NT; ++ct) sa[ct] = (f32x4){0.f, 0.f, 0.f, 0.f};
#pragma unroll
        for (int ct = 0; ct < NT; ++ct) {
            const char* kb = (const char*)Kl + (ct * 16 + fr) * 128;
            bf16x8 kf0 = *(const bf16x8*)(kb + ((fq * 16) ^ ((fr & 7) << 4)));
            bf16x8 kf1 = *(const bf16x8*)(kb + ((64 + fq * 16) ^ ((fr & 7) << 4)));
            sa[ct] = __builtin_amdgcn_mfma_f32_16x16x32_bf16(aq0, kf0, sa[ct], 0, 0, 0);
            sa[ct] = __builtin_amdgcn_mfma_f32_16x16x32_bf16(aq1, kf1, sa[ct], 0, 0, 0);
        }
        float mrow[4] = {-3e38f, -3e38f, -3e38f, -3e38f};
#pragma unroll
        for (int ct = 0; ct < NT; ++ct) {
            bool ok = (ct * 16 + fr) < N;
#pragma unroll
            for (int r = 0; r < 4; ++r) {
                float s = ok ? sa[ct][r] * 0.125f : -3e38f;
                sa[ct][r] = s;
                mrow[r] = fmaxf(mrow[r], s);
            }
        }
#pragma unroll
        for (int off = 1; off <= 8; off <<= 1)
#pragma unroll
            for (int r = 0; r < 4; ++r) mrow[r] = fmaxf(mrow[r], __shfl_xor(mrow[r], off));
        float ssum[4] = {0.f, 0.f, 0.f, 0.f};
#pragma unroll
        for (int ct = 0; ct < NT; ++ct)
#pragma unroll
            for (int r = 0; r < 4; ++r) {
                float p = __expf(sa[ct][r] - mrow[r]);
                sa[ct][r] = p;
                ssum[r] += p;
            }
#pragma unroll
        for (int off = 1; off <= 8; off <<= 1)
#pragma unroll
            for (int r = 0; r < 4; ++r) ssum[r] += __shfl_xor(ssum[r], off);
#pragma unroll
        for (int ct = 0; ct < NT; ++ct)
#pragma unroll
            for (int r = 0; r < 4; ++r)
                pw[(fq * 4 + r) * PS + ct * 16 + fr] = f2b(sa[ct][r]);
        f32x4 oa[4];
#pragma unroll
        for (int vt = 0; vt < 4; ++vt) oa[vt] = (f32x4){0.f, 0.f, 0.f, 0.f};
#pragma unroll
        for (int ks = 0; ks < KS; ++ks) {
            bf16x8 pa = *(const bf16x8*)(pw + fr * PS + ks * 32 + fq * 8);
#pragma unroll
            for (int vt = 0; vt < 4; ++vt) {
                bf16x8 vf = *(const bf16x8*)(&Vt[(vt * 16 + fr) * PS + ks * 32 + fq * 8]);
                oa[vt] = __builtin_amdgcn_mfma_f32_16x16x32_bf16(pa, vf, oa[vt], 0, 0, 0);
            }
        }
        float inv[4];
#pragma unroll
        for (int r = 0; r < 4; ++r) inv[r] = 1.f / ssum[r];
#pragma unroll
        for (int vt = 0; vt < 4; ++vt)
#pragma unroll
            for (int r = 0; r < 4; ++r) {
                int q = q0 + fq * 4 + r;
                if (q < N)
                    out[((size_t)b * N + q) * SO + h * 64 + vt * 16 + fr] =
                        f2b(oa[vt][r] * inv[r]);
            }
    }
}

// ---------------- stable argsort of 196 per batch ----------------
__global__ __launch_bounds__(256) void argsort_kernel(const float* __restrict__ rnd,
                                                      int* __restrict__ ord) {
    __shared__ float vals[196];
    int b = blockIdx.x, t = threadIdx.x;
    if (t < 196) vals[t] = rnd[b * 196 + t];
    __syncthreads();
    if (t < 196) {
        float v = vals[t];
        int rank = 0;
        for (int j = 0; j < 196; ++j) {
            float vj = vals[j];
            rank += (vj < v) || (vj == v && j < t);
        }
        ord[b * 196 + rank] = t;
    }
}

__global__ __launch_bounds__(256) void gather_unmasked(const unsigned short* __restrict__ patches,
                                                       const float* __restrict__ pos,
                                                       const int* __restrict__ ord,
                                                       float* __restrict__ xe) {
    int row = blockIdx.x;  // 0..3135
    int b = row / 49, i = row % 49;
    int src = ord[b * 196 + 147 + i];
    const unsigned short* pr = patches + ((size_t)(b * 196 + src) << 10);
    const float* pe = pos + ((size_t)src << 10);
    float* o = xe + ((size_t)row << 10);
    int d = threadIdx.x * 4;
    ushort4 pv = *(const ushort4*)(pr + d);
    float4 p4 = *(const float4*)(pe + d);
    float4 r;
    r.x = b2f(pv.x) + p4.x; r.y = b2f(pv.y) + p4.y;
    r.z = b2f(pv.z) + p4.z; r.w = b2f(pv.w) + p4.w;
    *(float4*)(o + d) = r;
}

// ---------------- LayerNorm: f32 in -> bf16 out ----------------
template <int L>
__global__ __launch_bounds__(256) void ln_kernel(const float* __restrict__ x,
                                                 unsigned short* __restrict__ y,
                                                 const float* __restrict__ sw,
                                                 const float* __restrict__ bw) {
    __shared__ float red[8];
    const int tid = threadIdx.x;
    const float* xr = x + (size_t)blockIdx.x * L;
    float sum = 0.f, sq = 0.f;
    for (int i = tid * 4; i < L; i += 1024) {
        float4 v = *(const float4*)(xr + i);
        sum += v.x + v.y + v.z + v.w;
        sq += v.x * v.x + v.y * v.y + v.z * v.z + v.w * v.w;
    }
    for (int off = 32; off; off >>= 1) {
        sum += __shfl_xor(sum, off);
        sq += __shfl_xor(sq, off);
    }
    int wave = tid >> 6, lane = tid & 63;
    if (lane == 0) { red[wave] = sum; red[4 + wave] = sq; }
    __syncthreads();
    float ts = red[0] + red[1] + red[2] + red[3];
    float tq = red[4] + red[5] + red[6] + red[7];
    float mean = ts / L;
    float inv = rsqrtf(tq / L - mean * mean + 1e-5f);
    unsigned short* yr = y + (size_t)blockIdx.x * L;
    for (int i = tid * 4; i < L; i += 1024) {
        float4 v = *(const float4*)(xr + i);
        float4 s4 = *(const float4*)(sw + i);
        float4 b4 = *(const float4*)(bw + i);
        ushort4 o;
        o.x = f2b((v.x - mean) * inv * s4.x + b4.x);
        o.y = f2b((v.y - mean) * inv * s4.y + b4.y);
        o.z = f2b((v.z - mean) * inv * s4.z + b4.z);
        o.w = f2b((v.w - mean) * inv * s4.w + b4.w);
        *(ushort4*)(yr + i) = o;
    }
}

__global__ __launch_bounds__(256) void scatter_tokens(const float* __restrict__ dec_tok,
                                                      const float* __restrict__ dec_pos,
                                                      const float* __restrict__ mask_tok,
                                                      const int* __restrict__ ord,
                                                      float* __restrict__ all_tok) {
    int e = blockIdx.x;  // 0..12543
    int b = e / 196, i = e % 196;
    int idx = ord[e];
    float* o = all_tok + ((size_t)(b * 196 + idx)) * 512;
    const float* dp = dec_pos + (size_t)idx * 512;
    int d = threadIdx.x * 4;
    if (d < 512) {
        float4 dv = *(const float4*)(dp + d);
        float4 sv;
        if (i < 147) sv = *(const float4*)(mask_tok + d);
        else sv = *(const float4*)(dec_tok + ((size_t)(b * 49 + (i - 147))) * 512 + d);
        float4 r = {sv.x + dv.x, sv.y + dv.y, sv.z + dv.z, sv.w + dv.w};
        *(float4*)(o + d) = r;
    }
}

__global__ __launch_bounds__(256) void loss_partial(const float* __restrict__ pred,
                                                    const unsigned short* __restrict__ patches,
                                                    const int* __restrict__ ord,
                                                    float* __restrict__ part) {
    __shared__ float red[8];
    float local = 0.f;
    const long long total = 9633792ll;  // 9408*1024
    for (long long e = (long long)blockIdx.x * 256 + threadIdx.x; e < total; e += 4096ll * 256) {
        int r = (int)(e >> 10), d = (int)(e & 1023);
        int b = r / 147, j = r % 147;
        int idx = ord[b * 196 + j];
        float t = b2f(patches[(((size_t)(b * 196 + idx)) << 10) + d]);
        float df = pred[e] - t;
        local += df * df;
    }
    for (int off = 32; off; off >>= 1) local += __shfl_xor(local, off);
    int wave = threadIdx.x >> 6, lane = threadIdx.x & 63;
    if (lane == 0) red[wave] = local;
    __syncthreads();
    if (threadIdx.x == 0) part[blockIdx.x] = red[0] + red[1] + red[2] + red[3];
}

__global__ __launch_bounds__(256) void loss_final(const float* __restrict__ part,
                                                  float* __restrict__ out) {
    __shared__ float red[8];
    float local = 0.f;
    for (int i = threadIdx.x; i < 4096; i += 256) local += part[i];
    for (int off = 32; off; off >>= 1) local += __shfl_xor(local, off);
    int wave = threadIdx.x >> 6, lane = threadIdx.x & 63;
    if (lane == 0) red[wave] = local;
    __syncthreads();
    if (threadIdx.x == 0) out[0] = (red[0] + red[1] + red[2] + red[3]) / 9633792.0f;
}

extern "C" void kernel_launch(void* const* d_in, const int* in_sizes, int n_in, void* d_out,
                              int out_size, void* d_ws, size_t ws_size, hipStream_t stream) {
    const float* images = (const float*)d_in[0];
    const float* rnd = (const float*)d_in[1];
    const float* patch_W = (const float*)d_in[2];
    const float* patch_b = (const float*)d_in[3];
    const float* pos_emb = (const float*)d_in[4];
    const float* enc_ln1s = (const float*)d_in[5];
    const float* enc_ln1b = (const float*)d_in[6];
    const float* enc_Wqkv = (const float*)d_in[7];
    const float* enc_Wo = (const float*)d_in[8];
    const float* enc_ln2s = (const float*)d_in[9];
    const float* enc_ln2b = (const float*)d_in[10];
    const float* enc_W1 = (const float*)d_in[11];
    const float* enc_b1 = (const float*)d_in[12];
    const float* enc_W2 = (const float*)d_in[13];
    const float* enc_b2 = (const float*)d_in[14];
    const float* enc_lnfs = (const float*)d_in[15];
    const float* enc_lnfb = (const float*)d_in[16];
    const float* e2d_W = (const float*)d_in[17];
    const float* e2d_b = (const float*)d_in[18];
    const float* mask_tok = (const float*)d_in[19];
    const float* dec_pos = (const float*)d_in[20];
    const float* dec_ln1s = (const float*)d_in[21];
    const float* dec_ln1b = (const float*)d_in[22];
    const float* dec_Wqkv = (const float*)d_in[23];
    const float* dec_Wo = (const float*)d_in[24];
    const float* dec_ln2s = (const float*)d_in[25];
    const float* dec_ln2b = (const float*)d_in[26];
    const float* dec_W1 = (const float*)d_in[27];
    const float* dec_b1 = (const float*)d_in[28];
    const float* dec_W2 = (const float*)d_in[29];
    const float* dec_b2 = (const float*)d_in[30];
    const float* dec_lnfs = (const float*)d_in[31];
    const float* dec_lnfb = (const float*)d_in[32];
    const float* pix_W = (const float*)d_in[33];
    const float* pix_b = (const float*)d_in[34];

    char* ws = (char*)d_ws;
    unsigned short* patches = (unsigned short*)(ws + OFF_PATCH);
    float* Rx = (float*)(ws + OFF_X);
    unsigned short* Rln = (unsigned short*)(ws + OFF_LN);
    unsigned short* RqkvB = (unsigned short*)(ws + OFF_QKV);
    float* RqkvF = (float*)(ws + OFF_QKV);
    unsigned short* Rhid = (unsigned short*)(ws + OFF_HID);
    unsigned short* wp = (unsigned short*)(ws + OFF_WP);
    int* ord = (int*)(ws + OFF_ORD);
    float* part = (float*)(ws + OFF_PART);
    float* out = (float*)d_out;

    // ---- merged weight pack (15 weights, one launch) ----
    PackArgs pa;
    int nd = 0, tiles = 0;
    auto ADDP = [&](const float* src, unsigned long long wpo, int K, int N) {
        pa.src[nd] = src; pa.dstOff[nd] = wpo; pa.K[nd] = K; pa.N[nd] = N;
        pa.tileStart[nd] = tiles;
        tiles += (K >> 5) * (N >> 5);
        ++nd;
    };
    ADDP(patch_W, WP_PATCH, 768, 1024);
    for (int l = 0; l < 2; ++l) {
        ADDP(enc_Wqkv + (size_t)l * 1024 * 3072, WP_ENC_QKV + (size_t)l * 3145728, 1024, 3072);
        ADDP(enc_Wo + (size_t)l * 1024 * 1024, WP_ENC_WO + (size_t)l * 1048576, 1024, 1024);
        ADDP(enc_W1 + (size_t)l * 1024 * 4096, WP_ENC_W1 + (size_t)l * 4194304, 1024, 4096);
        ADDP(enc_W2 + (size_t)l * 4096 * 1024, WP_ENC_W2 + (size_t)l * 4194304, 4096, 1024);
    }
    ADDP(e2d_W, WP_E2D, 1024, 512);
    ADDP(dec_Wqkv, WP_DEC_QKV, 512, 1536);
    ADDP(dec_Wo, WP_DEC_WO, 512, 512);
    ADDP(dec_W1, WP_DEC_W1, 512, 2048);
    ADDP(dec_W2, WP_DEC_W2, 2048, 512);
    ADDP(pix_W, WP_PIX, 512, 1024);
    pa.tileStart[nd] = tiles;
    pack_all<<<tiles, 256, 0, stream>>>(pa, wp);

    // gemmV: 128x128 8-wave high-occupancy. S = split-K (atomic when >1).
    auto GEMM = [&](int om, const unsigned short* A, size_t wpo, void* C, const float* bias,
                    int M, int N, int K, int S, bool small, const int* gord = nullptr) {
        const unsigned short* Bt = wp + wpo;
        int Kc = K / S;
        if (!small) {
            dim3 g(N / 128, (M + 127) / 128, S);
            if (gord) gemmV<OM_F32, false, true><<<g, 512, 0, stream>>>(A, Bt, C, bias, gord, M, N, K, Kc);
            else if (S > 1) gemmV<OM_ACC, true, false><<<g, 512, 0, stream>>>(A, Bt, C, bias, nullptr, M, N, K, Kc);
            else if (om == OM_BF16) gemmV<OM_BF16, false, false><<<g, 512, 0, stream>>>(A, Bt, C, bias, nullptr, M, N, K, Kc);
            else if (om == OM_F32) gemmV<OM_F32, false, false><<<g, 512, 0, stream>>>(A, Bt, C, bias, nullptr, M, N, K, Kc);
            else if (om == OM_ACC) gemmV<OM_ACC, false, false><<<g, 512, 0, stream>>>(A, Bt, C, bias, nullptr, M, N, K, Kc);
            else gemmV<OM_GELU, false, false><<<g, 512, 0, stream>>>(A, Bt, C, bias, nullptr, M, N, K, Kc);
        } else {
            dim3 g(N / 128, (M + 127) / 128, 1);
            if (om == OM_F32) gemm3s<OM_F32><<<g, 256, 0, stream>>>(A, Bt, C, bias, M, N, K);
            else gemm3s<OM_BF16><<<g, 256, 0, stream>>>(A, Bt, C, bias, M, N, K);
        }
    };

    // 1) patchify (Xp bf16 in Rhid), patches = Xp @ patch_W + b  (bf16)
    patchify_kernel<<<4096, 256, 0, stream>>>(images, Rhid);
    GEMM(OM_BF16, Rhid, WP_PATCH, patches, patch_b, 12544, 1024, 768, 1, false);
    // 2) argsort + gather unmasked (fp32 residual stream)
    argsort_kernel<<<64, 256, 0, stream>>>(rnd, ord);
    gather_unmasked<<<3136, 256, 0, stream>>>(patches, pos_emb, ord, Rx);

    // 3) encoder
    for (int l = 0; l < 2; ++l) {
        ln_kernel<1024><<<3136, 256, 0, stream>>>(Rx, Rln, enc_ln1s + l * 1024,
                                                  enc_ln1b + l * 1024);
        GEMM(OM_BF16, Rln, WP_ENC_QKV + (size_t)l * 3145728, RqkvB, nullptr, 3136, 3072, 1024,
             1, false);
        attn_mfma<49, 16, 4><<<64 * 16, 256, 0, stream>>>(RqkvB, Rhid);
        GEMM(OM_ACC, Rhid, WP_ENC_WO + (size_t)l * 1048576, Rx, nullptr, 3136, 1024, 1024, 4,
             false);
        ln_kernel<1024><<<3136, 256, 0, stream>>>(Rx, Rln, enc_ln2s + l * 1024,
                                                  enc_ln2b + l * 1024);
        GEMM(OM_GELU, Rln, WP_ENC_W1 + (size_t)l * 4194304, Rhid, enc_b1 + l * 4096, 3136,
             4096, 1024, 1, false);
        GEMM(OM_ACC, Rhid, WP_ENC_W2 + (size_t)l * 4194304, Rx, enc_b2 + l * 1024, 3136, 1024,
             4096, 4, false);
    }
    ln_kernel<1024><<<3136, 256, 0, stream>>>(Rx, Rln, enc_lnfs, enc_lnfb);

    // 4) e2d -> dec_tok (f32, in QKV region), scatter into decoder residual (f32)
    GEMM(OM_F32, Rln, WP_E2D, RqkvF, e2d_b, 3136, 512, 1024, 1, true);
    scatter_tokens<<<12544, 256, 0, stream>>>(RqkvF, dec_pos, mask_tok, ord, Rx);

    // 5) decoder
    ln_kernel<512><<<12544, 256, 0, stream>>>(Rx, Rln, dec_ln1s, dec_ln1b);
    GEMM(OM_BF16, Rln, WP_DEC_QKV, RqkvB, nullptr, 12544, 1536, 512, 1, false);
    attn_mfma<196, 8, 8><<<64 * 8, 512, 0, stream>>>(RqkvB, Rhid);
    GEMM(OM_ACC, Rhid, WP_DEC_WO, Rx, nullptr, 12544, 512, 512, 2, false);
    ln_kernel<512><<<12544, 256, 0, stream>>>(Rx, Rln, dec_ln2s, dec_ln2b);
    GEMM(OM_GELU, Rln, WP_DEC_W1, Rhid, dec_b1, 12544, 2048, 512, 1, false);
    GEMM(OM_ACC, Rhid, WP_DEC_W2, Rx, dec_b2, 12544, 512, 2048, 2, false);
    ln_kernel<512><<<12544, 256, 0, stream>>>(Rx, Rln, dec_lnfs, dec_lnfb);

    // 6) pix head with fused masked-gather (pred f32 in QKV region), MSE
    GEMM(OM_F32, Rln, WP_PIX, RqkvF, pix_b, 9408, 1024, 512, 1, false, ord);
    loss_partial<<<4096, 256, 0, stream>>>(RqkvF, patches, ord, part);
    loss_final<<<1, 256, 0, stream>>>(part, out);
}